// Round 6
// baseline (3318.082 us; speedup 1.0000x reference)
//
#include <hip/hip_runtime.h>
#include <cstddef>

#define DEVINF __builtin_inff()

typedef __attribute__((ext_vector_type(8))) short bf16x8;
typedef __attribute__((ext_vector_type(4))) float f32x4;
typedef __attribute__((ext_vector_type(2))) float f32x2;

__device__ __forceinline__ unsigned short f2bf(float x) {
  unsigned u = __float_as_uint(x);
  return (unsigned short)((u + 0x7fff + ((u >> 16) & 1)) >> 16);
}
__device__ __forceinline__ float bf2f(unsigned short h) {
  return __uint_as_float(((unsigned)h) << 16);
}
__device__ __forceinline__ void split_bf(float x, unsigned short& hi, unsigned short& lo) {
  hi = f2bf(x);
  lo = f2bf(x - bf2f(hi));
}

// ---------------------------------------------------------------------------
// FPS cooperative step (round-0 proven form): per-wave update, DPP ladder to
// lane 63. Key = (val_bits<<32)|~idx -> (max value, min index), exact u32
// compare, order-independent.
// ---------------------------------------------------------------------------
#define FPS_RED_LEVEL(CTRL)                                                      \
  {                                                                              \
    int th = __builtin_amdgcn_update_dpp((int)hi, (int)hi, CTRL, 0xf, 0xf, false); \
    int tl = __builtin_amdgcn_update_dpp((int)lo, (int)lo, CTRL, 0xf, 0xf, false); \
    bool take = ((unsigned)th > hi) || (((unsigned)th == hi) && ((unsigned)tl > lo)); \
    hi = take ? (unsigned)th : hi;                                               \
    lo = take ? (unsigned)tl : lo;                                               \
  }

template <int PPLH, int NCH>
__device__ __forceinline__ unsigned long long fps_wave_step(
    f32x2* qx, f32x2* qy, f32x2* qz, f32x2* d, float lx, float ly, float lz,
    int lane, int ibase) {
#pragma clang fp contract(off)
  const int CH = PPLH / NCH;
  float bv[NCH];
  int bi[NCH];
#pragma unroll
  for (int c = 0; c < NCH; ++c) { bv[c] = -DEVINF; bi[c] = 0x7fffffff; }
  f32x2 lxv = {lx, lx}, lyv = {ly, ly}, lzv = {lz, lz};
#pragma unroll
  for (int h = 0; h < PPLH; ++h) {
    const int c = h / CH;
    f32x2 dx = qx[h] - lxv, dy = qy[h] - lyv, dz = qz[h] - lzv;
    f32x2 t0 = dx * dx, t1 = dy * dy, t2 = dz * dz;
    f32x2 d2 = (t0 + t1) + t2;
    f32x2 dn;
    dn.x = fminf(d[h].x, d2.x);
    dn.y = fminf(d[h].y, d2.y);
    d[h] = dn;
    int i0 = ibase + (2 * h) * 64 + lane;
    if (dn.x > bv[c]) { bv[c] = dn.x; bi[c] = i0; }
    if (dn.y > bv[c]) { bv[c] = dn.y; bi[c] = i0 + 64; }
  }
  unsigned hi, lo;
  if (NCH == 4) {
    unsigned h0 = __float_as_uint(bv[0]), l0 = ~(unsigned)bi[0];
    unsigned h1 = __float_as_uint(bv[1]), l1 = ~(unsigned)bi[1];
    unsigned h2 = __float_as_uint(bv[2]), l2 = ~(unsigned)bi[2];
    unsigned h3 = __float_as_uint(bv[3]), l3 = ~(unsigned)bi[3];
    bool t01 = (h1 > h0) || ((h1 == h0) && (l1 > l0));
    unsigned ha = t01 ? h1 : h0, la = t01 ? l1 : l0;
    bool t23 = (h3 > h2) || ((h3 == h2) && (l3 > l2));
    unsigned hb = t23 ? h3 : h2, lb = t23 ? l3 : l2;
    bool tab = (hb > ha) || ((hb == ha) && (lb > la));
    hi = tab ? hb : ha;
    lo = tab ? lb : la;
  } else {
    const int c1 = (NCH > 1) ? 1 : 0;
    unsigned h0 = __float_as_uint(bv[0]), l0 = ~(unsigned)bi[0];
    unsigned h1 = __float_as_uint(bv[c1]), l1 = ~(unsigned)bi[c1];
    bool t01 = (h1 > h0) || ((h1 == h0) && (l1 > l0));
    hi = t01 ? h1 : h0;
    lo = t01 ? l1 : l0;
  }
  FPS_RED_LEVEL(0x111)  // row_shr:1
  FPS_RED_LEVEL(0x112)  // row_shr:2
  FPS_RED_LEVEL(0x114)  // row_shr:4
  FPS_RED_LEVEL(0x118)  // row_shr:8
  FPS_RED_LEVEL(0x142)  // row_bcast:15
  FPS_RED_LEVEL(0x143)  // row_bcast:31
  return (((unsigned long long)hi) << 32) | lo;  // valid on lane 63
}

// ---------------------------------------------------------------------------
// prep jobs (bf16 hi/lo transposed weight planes). Unused slots: blk0 = INT_MAX.
// ---------------------------------------------------------------------------
struct PrepJobs {
  const float* src[9];
  unsigned short* hi[9];
  unsigned short* lo[9];
  int K[9], N[9], rl[9];
  int blk0[10];
};

__device__ __forceinline__ void do_prep_chunk(const PrepJobs& jb, int blk, int tid) {
  int j = 0;
#pragma unroll
  for (int t = 1; t < 9; ++t)
    if (blk >= jb.blk0[t]) j = t;
  int idx = (blk - jb.blk0[j]) * 256 + tid;
  int rl = jb.rl[j], N = jb.N[j], K = jb.K[j];
  if (idx >= N * rl) return;
  int n = idx / rl, k = idx - n * rl;
  float v = (k < K) ? jb.src[j][(size_t)k * N + n] : 0.f;
  unsigned short h, l;
  split_bf(v, h, l);
  jb.hi[j][idx] = h;
  jb.lo[j][idx] = l;
}

__global__ __launch_bounds__(256) void prep_kernel(PrepJobs jb) {
  do_prep_chunk(jb, (int)blockIdx.x, (int)threadIdx.x);
}

// ---------------------------------------------------------------------------
// legacy fps1 (fallback path): 2048 -> 1024 centers, R0 4-wave barrier form.
// ---------------------------------------------------------------------------
__global__ __launch_bounds__(256, 1) void fps1_kernel(
    const float* __restrict__ pos, float* __restrict__ p1) {
#pragma clang fp contract(off)
  const int tid = threadIdx.x;
  const int b = blockIdx.x;
  const int w = tid >> 6, lane = tid & 63;
  __shared__ __align__(16) float4 p4[2048];
  __shared__ __align__(16) float4 carr[1024];
  __shared__ __align__(16) unsigned long long kv[2][4];
  f32x2 qx[4], qy[4], qz[4], d[4];
  const int ibase = w * 512;
#pragma unroll
  for (int h = 0; h < 4; ++h) {
    int i0 = ibase + (2 * h) * 64 + lane, i1 = i0 + 64;
    const float* a = pos + ((size_t)b * 2048 + i0) * 3;
    const float* c = pos + ((size_t)b * 2048 + i1) * 3;
    float x0 = a[0], y0 = a[1], z0 = a[2];
    float x1 = c[0], y1 = c[1], z1 = c[2];
    qx[h].x = x0; qx[h].y = x1;
    qy[h].x = y0; qy[h].y = y1;
    qz[h].x = z0; qz[h].y = z1;
    d[h].x = DEVINF; d[h].y = DEVINF;
    p4[i0] = float4{x0, y0, z0, 0.f};
    p4[i1] = float4{x1, y1, z1, 0.f};
  }
  __syncthreads();
  int last = 0;
  for (int s = 0; s < 1024; ++s) {
    float4 c4 = p4[last];
    if (tid == 0) carr[s] = c4;
    unsigned long long k =
        fps_wave_step<4, 4>(qx, qy, qz, d, c4.x, c4.y, c4.z, lane, ibase);
    if (lane == 63) kv[s & 1][w] = k;
    __syncthreads();
    unsigned long long k0 = kv[s & 1][0], k1 = kv[s & 1][1];
    unsigned long long k2 = kv[s & 1][2], k3 = kv[s & 1][3];
    unsigned long long ka = k0 > k1 ? k0 : k1;
    unsigned long long kb = k2 > k3 ? k2 : k3;
    unsigned long long kk = ka > kb ? ka : kb;
    last = (int)~(unsigned)kk;
  }
  for (int i = tid; i < 1024; i += 256) {
    float4 c = carr[i];
    p1[((size_t)b * 1024 + i) * 3 + 0] = c.x;
    p1[((size_t)b * 1024 + i) * 3 + 1] = c.y;
    p1[((size_t)b * 1024 + i) * 3 + 2] = c.z;
  }
}

// ---------------------------------------------------------------------------
// fps2 core (R0 barrier form): q4 pre-staged by caller; fills carr, writes p2.
// ---------------------------------------------------------------------------
__device__ __forceinline__ void fps2_core(float4* q4, float4* carr,
                                          unsigned long long (*kv2)[4],
                                          float* __restrict__ p2b, int tid,
                                          int w, int lane) {
#pragma clang fp contract(off)
  f32x2 qx[2], qy[2], qz[2], d[2];
  const int ibase = w * 256;
#pragma unroll
  for (int h = 0; h < 2; ++h) {
    int i0 = ibase + (2 * h) * 64 + lane, i1 = i0 + 64;
    float4 a = q4[i0], c = q4[i1];
    qx[h].x = a.x; qx[h].y = c.x;
    qy[h].x = a.y; qy[h].y = c.y;
    qz[h].x = a.z; qz[h].y = c.z;
    d[h].x = DEVINF; d[h].y = DEVINF;
  }
  int last = 0;
  for (int s = 0; s < 256; ++s) {
    float4 c4 = q4[last];
    if (tid == 0) carr[s] = c4;
    unsigned long long k =
        fps_wave_step<2, 2>(qx, qy, qz, d, c4.x, c4.y, c4.z, lane, ibase);
    if (lane == 63) kv2[s & 1][w] = k;
    __syncthreads();
    unsigned long long k0 = kv2[s & 1][0], k1 = kv2[s & 1][1];
    unsigned long long k2 = kv2[s & 1][2], k3 = kv2[s & 1][3];
    unsigned long long ka = k0 > k1 ? k0 : k1;
    unsigned long long kb = k2 > k3 ? k2 : k3;
    unsigned long long kk = ka > kb ? ka : kb;
    last = (int)~(unsigned)kk;
  }
  {
    float4 c = carr[tid];
    if (tid < 256) {
      p2b[3 * tid + 0] = c.x;
      p2b[3 * tid + 1] = c.y;
      p2b[3 * tid + 2] = c.z;
    }
  }
}

// ---------------------------------------------------------------------------
// MFMA building blocks — B fragments SOFTWARE-PIPELINED one (ks,t) step ahead.
// ---------------------------------------------------------------------------
template <int KS, int T>
__device__ __forceinline__ void mfma_allm(
    const unsigned short* __restrict__ inHi, const unsigned short* __restrict__ inLo,
    int sIn, const unsigned short* __restrict__ wHi,
    const unsigned short* __restrict__ wLo, int rl, const float* __restrict__ bias,
    int n0, int lane, f32x4 acc[4][T]) {
  const int col = lane & 15, quad = lane >> 4;
#pragma unroll
  for (int t = 0; t < T; ++t) {
    float bv = bias[n0 + t * 16 + col];
#pragma unroll
    for (int mt = 0; mt < 4; ++mt) {
      acc[mt][t].x = bv; acc[mt][t].y = bv; acc[mt][t].z = bv; acc[mt][t].w = bv;
    }
  }
  size_t b0 = (size_t)(n0 + col) * rl + quad * 8;
  bf16x8 bh = *(const bf16x8*)(wHi + b0);
  bf16x8 bl = *(const bf16x8*)(wLo + b0);
#pragma unroll 1
  for (int ks = 0; ks < KS; ++ks) {
    bf16x8 ah[4], al[4];
#pragma unroll
    for (int mt = 0; mt < 4; ++mt) {
      int aoff = (mt * 16 + col) * sIn + ks * 32 + quad * 8;
      ah[mt] = *(const bf16x8*)(inHi + aoff);
      al[mt] = *(const bf16x8*)(inLo + aoff);
    }
#pragma unroll
    for (int t = 0; t < T; ++t) {
      int nks = (t + 1 < T) ? ks : ks + 1;
      int nt = (t + 1 < T) ? t + 1 : 0;
      if (nks > KS - 1) nks = KS - 1;  // clamp: value unused on last step
      size_t nboff = (size_t)(n0 + nt * 16 + col) * rl + nks * 32 + quad * 8;
      bf16x8 nh = *(const bf16x8*)(wHi + nboff);
      bf16x8 nl = *(const bf16x8*)(wLo + nboff);
#pragma unroll
      for (int mt = 0; mt < 4; ++mt) {
        acc[mt][t] = __builtin_amdgcn_mfma_f32_16x16x32_bf16(ah[mt], bh, acc[mt][t], 0, 0, 0);
        acc[mt][t] = __builtin_amdgcn_mfma_f32_16x16x32_bf16(ah[mt], bl, acc[mt][t], 0, 0, 0);
        acc[mt][t] = __builtin_amdgcn_mfma_f32_16x16x32_bf16(al[mt], bh, acc[mt][t], 0, 0, 0);
      }
      bh = nh;
      bl = nl;
    }
  }
}

template <int T>
__device__ __forceinline__ void store_allm(const f32x4 acc[4][T], int n0,
                                           unsigned short* outHi,
                                           unsigned short* outLo, int sOut,
                                           int lane) {
  const int col = lane & 15, quad = lane >> 4;
#pragma unroll
  for (int mt = 0; mt < 4; ++mt)
#pragma unroll
    for (int t = 0; t < T; ++t)
#pragma unroll
      for (int r = 0; r < 4; ++r) {
        int edge = mt * 16 + quad * 4 + r;
        float v = fmaxf(acc[mt][t][r], 0.f);
        unsigned short h, l;
        split_bf(v, h, l);
        outHi[edge * sOut + n0 + t * 16 + col] = h;
        outLo[edge * sOut + n0 + t * 16 + col] = l;
      }
}

template <int T>
__device__ __forceinline__ void outpool_allm(const f32x4 acc[4][T], int n0,
                                             float* __restrict__ outp, int nvalid,
                                             int lane) {
  const int col = lane & 15, quad = lane >> 4;
#pragma unroll
  for (int t = 0; t < T; ++t) {
    float m = -DEVINF;
#pragma unroll
    for (int mt = 0; mt < 4; ++mt)
#pragma unroll
      for (int r = 0; r < 4; ++r) {
        int edge = mt * 16 + quad * 4 + r;
        float v = fmaxf(acc[mt][t][r], 0.f);
        if (edge >= nvalid) v = -DEVINF;
        m = fmaxf(m, v);
      }
    m = fmaxf(m, __shfl_xor(m, 16, 64));
    m = fmaxf(m, __shfl_xor(m, 32, 64));
    if (quad == 0) outp[n0 + t * 16 + col] = m;
  }
}

// single-m-tile variants (gsa), B-pipelined identically
template <int KS, int T>
__device__ __forceinline__ void mfma_1m(
    const unsigned short* __restrict__ inHi, const unsigned short* __restrict__ inLo,
    int sIn, const unsigned short* __restrict__ wHi,
    const unsigned short* __restrict__ wLo, int rl, const float* __restrict__ bias,
    int n0, int lane, f32x4 acc[T]) {
  const int col = lane & 15, quad = lane >> 4;
#pragma unroll
  for (int t = 0; t < T; ++t) {
    float bv = bias[n0 + t * 16 + col];
    acc[t].x = bv; acc[t].y = bv; acc[t].z = bv; acc[t].w = bv;
  }
  size_t b0 = (size_t)(n0 + col) * rl + quad * 8;
  bf16x8 bh = *(const bf16x8*)(wHi + b0);
  bf16x8 bl = *(const bf16x8*)(wLo + b0);
#pragma unroll 1
  for (int ks = 0; ks < KS; ++ks) {
    int aoff = col * sIn + ks * 32 + quad * 8;
    bf16x8 ah = *(const bf16x8*)(inHi + aoff);
    bf16x8 al = *(const bf16x8*)(inLo + aoff);
#pragma unroll
    for (int t = 0; t < T; ++t) {
      int nks = (t + 1 < T) ? ks : ks + 1;
      int nt = (t + 1 < T) ? t + 1 : 0;
      if (nks > KS - 1) nks = KS - 1;
      size_t nboff = (size_t)(n0 + nt * 16 + col) * rl + nks * 32 + quad * 8;
      bf16x8 nh = *(const bf16x8*)(wHi + nboff);
      bf16x8 nl = *(const bf16x8*)(wLo + nboff);
      acc[t] = __builtin_amdgcn_mfma_f32_16x16x32_bf16(ah, bh, acc[t], 0, 0, 0);
      acc[t] = __builtin_amdgcn_mfma_f32_16x16x32_bf16(ah, bl, acc[t], 0, 0, 0);
      acc[t] = __builtin_amdgcn_mfma_f32_16x16x32_bf16(al, bh, acc[t], 0, 0, 0);
      bh = nh;
      bl = nl;
    }
  }
}

template <int T>
__device__ __forceinline__ void store_1m(const f32x4 acc[T], int n0,
                                         unsigned short* outHi,
                                         unsigned short* outLo, int sOut, int lane) {
  const int col = lane & 15, quad = lane >> 4;
#pragma unroll
  for (int t = 0; t < T; ++t)
#pragma unroll
    for (int r = 0; r < 4; ++r) {
      int p = quad * 4 + r;
      float v = fmaxf(acc[t][r], 0.f);
      unsigned short h, l;
      split_bf(v, h, l);
      outHi[p * sOut + n0 + t * 16 + col] = h;
      outLo[p * sOut + n0 + t * 16 + col] = l;
    }
}

// ---------------------------------------------------------------------------
// SA1 body (R0-proven): ball query + staging + 3-layer MFMA MLP + maxpool.
// Shared between the legacy sa1_kernel and the fused consumer path.
// ---------------------------------------------------------------------------
__device__ __forceinline__ void sa1_body(
    int b, int bs, float cx, float cy, float cz,
    const float* __restrict__ x, const float* __restrict__ pos,
    const unsigned short* __restrict__ w1h, const unsigned short* __restrict__ w1l,
    const unsigned short* __restrict__ w2h, const unsigned short* __restrict__ w2l,
    const unsigned short* __restrict__ w3h, const unsigned short* __restrict__ w3l,
    const float* __restrict__ b1, const float* __restrict__ b2,
    const float* __restrict__ b3, float* __restrict__ out,
    unsigned short* bufA_hi, unsigned short* bufA_lo,
    unsigned short* bufB_hi, unsigned short* bufB_lo, int* nb, int* tot) {
  const int N = 2048;
  const float r2 = (float)(0.2 * 0.2);
  const int tid = threadIdx.x;
  const int w = tid >> 6, lane = tid & 63;
  nb[lane] = 0;
  unsigned long long mloc[8];
  {
#pragma clang fp contract(off)
#pragma unroll
    for (int it = 0; it < 8; ++it) {
      int i = (w * 8 + it) * 64 + lane;
      const float* p = pos + ((size_t)b * N + i) * 3;
      float dx = p[0] - cx, dy = p[1] - cy, dz = p[2] - cz;
      float t0 = dx * dx, t1 = dy * dy, t2 = dz * dz;
      float d2 = (t0 + t1) + t2;
      mloc[it] = __ballot(d2 <= r2);
    }
  }
  {
    int mytot = 0;
#pragma unroll
    for (int it = 0; it < 8; ++it) mytot += (int)__popcll(mloc[it]);
    if (lane == 0) tot[w] = mytot;
  }
  __syncthreads();
  const int t0s = tot[0], t1s = tot[1], t2s = tot[2], t3s = tot[3];
  {
    int cnt = (w > 0 ? t0s : 0) + (w > 1 ? t1s : 0) + (w > 2 ? t2s : 0);
#pragma unroll
    for (int it = 0; it < 8; ++it) {
      unsigned long long m = mloc[it];
      bool inr = (m >> lane) & 1;
      int posn = cnt + (int)__popcll(m & ((1ull << lane) - 1ull));
      if (inr && posn < 64) nb[posn] = (w * 8 + it) * 64 + lane;
      cnt += (int)__popcll(m);
    }
  }
  const int total = t0s + t1s + t2s + t3s;
  const int nvalid = total < 64 ? total : 64;
  __syncthreads();  // nb complete & visible
  {
    int j = nb[lane];
    if (w < 3) {
      const float* xr = x + ((size_t)b * N + j) * 9 + w * 3;
      float f0 = xr[0], f1 = xr[1], f2 = xr[2];
      unsigned short h, l;
      split_bf(f0, h, l); bufA_hi[lane * 72 + w * 3 + 0] = h; bufA_lo[lane * 72 + w * 3 + 0] = l;
      split_bf(f1, h, l); bufA_hi[lane * 72 + w * 3 + 1] = h; bufA_lo[lane * 72 + w * 3 + 1] = l;
      split_bf(f2, h, l); bufA_hi[lane * 72 + w * 3 + 2] = h; bufA_lo[lane * 72 + w * 3 + 2] = l;
    } else {
      const float* pr = pos + ((size_t)b * N + j) * 3;
      float rr[3] = {pr[0] - cx, pr[1] - cy, pr[2] - cz};
#pragma unroll
      for (int c = 0; c < 3; ++c) {
        unsigned short h, l;
        split_bf(rr[c], h, l);
        bufA_hi[lane * 72 + 9 + c] = h;
        bufA_lo[lane * 72 + 9 + c] = l;
      }
#pragma unroll
      for (int k = 12; k < 32; ++k) {
        bufA_hi[lane * 72 + k] = 0;
        bufA_lo[lane * 72 + k] = 0;
      }
    }
  }
  __syncthreads();
  {  // L1: K=32(12), N=64; wave n-slice [w*16, w*16+16)
    f32x4 acc[4][1];
    mfma_allm<1, 1>(bufA_hi, bufA_lo, 72, w1h, w1l, 40, b1, w * 16, lane, acc);
    store_allm<1>(acc, w * 16, bufB_hi, bufB_lo, 72, lane);
  }
  __syncthreads();
  {  // L2: K=64, N=64; reads B, writes A
    f32x4 acc[4][1];
    mfma_allm<2, 1>(bufB_hi, bufB_lo, 72, w2h, w2l, 72, b2, w * 16, lane, acc);
    store_allm<1>(acc, w * 16, bufA_hi, bufA_lo, 72, lane);
  }
  __syncthreads();
  {  // L3: K=64, N=128; wave n-slice [w*32, w*32+32) + pool
    f32x4 acc[4][2];
    mfma_allm<2, 2>(bufA_hi, bufA_lo, 72, w3h, w3l, 72, b3, w * 32, lane, acc);
    outpool_allm<2>(acc, w * 32, out + (size_t)bs * 128, nvalid, lane);
  }
}

// ---------------------------------------------------------------------------
// legacy sa1 (fallback): blocks 0..15 fps2, rest sa1_body with plain ctr reads.
// ---------------------------------------------------------------------------
__global__ __launch_bounds__(256, 4) void sa1_kernel(
    const float* __restrict__ x, const float* __restrict__ pos,
    const float* __restrict__ ctr, float* __restrict__ p2,
    const unsigned short* __restrict__ w1h, const unsigned short* __restrict__ w1l,
    const unsigned short* __restrict__ w2h, const unsigned short* __restrict__ w2l,
    const unsigned short* __restrict__ w3h, const unsigned short* __restrict__ w3l,
    const float* __restrict__ b1, const float* __restrict__ b2,
    const float* __restrict__ b3, float* __restrict__ out) {
  const int tid = threadIdx.x;
  const int w = tid >> 6, lane = tid & 63;
  __shared__ __align__(16) unsigned short smem[4 * 4608];
  __shared__ int nb[64];
  __shared__ int tot[4];
  __shared__ __align__(16) unsigned long long kv2s[2][4];
  if (blockIdx.x < 16) {
    const int bb = blockIdx.x;
    float4* q4 = (float4*)smem;
    float4* carr = (float4*)(smem + 8192);
    for (int i = tid; i < 1024; i += 256) {
      const float* pr = ctr + ((size_t)bb * 1024 + i) * 3;
      q4[i] = float4{pr[0], pr[1], pr[2], 0.f};
    }
    __syncthreads();
    fps2_core(q4, carr, kv2s, p2 + (size_t)bb * 768, tid, w, lane);
    return;
  }
  const int bs = blockIdx.x - 16;
  const int b = bs >> 10;
  const float cx = ctr[bs * 3 + 0], cy = ctr[bs * 3 + 1], cz = ctr[bs * 3 + 2];
  sa1_body(b, bs, cx, cy, cz, x, pos, w1h, w1l, w2h, w2l, w3h, w3l, b1, b2, b3,
           out, smem, smem + 4608, smem + 9216, smem + 13824, nb, tot);
}

// ---------------------------------------------------------------------------
// FUSED cooperative kernel: fps1 producers (blocks 0..15) publish centers
// progressively via agent-scope atomics; fps2 (16..31) waits for full p1;
// consumers (32..) pull sa1 work items in production order from a global
// counter. No grid sync; co-residency guaranteed by cooperative launch.
// Publish protocol: xyz stores (relaxed agent atomics, coherent) for center s
// at iter s; prog[b]=s published at iter s AFTER an explicit
// s_waitcnt vmcnt(0) (waits on iter s-1's stores, ~1 iter old -> ~0 stall).
// ---------------------------------------------------------------------------
struct FusedParams {
  const float* x; const float* pos; float* p1; float* p2;
  const unsigned short *w1h, *w1l, *w2h, *w2l, *w3h, *w3l;
  const float *b1, *b2, *b3;
  float* x1;
  int* prog; int* wctr;
  PrepJobs jb;   // jobs for sa2/gsa weights (6 used)
  int nprep;
  int ncons;
};

__global__ __launch_bounds__(256, 4) void fused_kernel(FusedParams P) {
  const int tid = threadIdx.x;
  const int w = tid >> 6, lane = tid & 63;
  __shared__ __align__(16) char lds[37184];
  if (blockIdx.x < 16) {
    // ----------------------- fps1 producer -----------------------
#pragma clang fp contract(off)
    __builtin_amdgcn_s_setprio(3);  // serial critical path: outprioritize co-resident consumers
    const int b = blockIdx.x;
    float4* p4 = (float4*)lds;
    unsigned long long(*kv)[4] = (unsigned long long(*)[4])(lds + 32768);
    f32x2 qx[4], qy[4], qz[4], d[4];
    const int ibase = w * 512;
#pragma unroll
    for (int h = 0; h < 4; ++h) {
      int i0 = ibase + (2 * h) * 64 + lane, i1 = i0 + 64;
      const float* a = P.pos + ((size_t)b * 2048 + i0) * 3;
      const float* c = P.pos + ((size_t)b * 2048 + i1) * 3;
      float x0 = a[0], y0 = a[1], z0 = a[2];
      float x1 = c[0], y1 = c[1], z1 = c[2];
      qx[h].x = x0; qx[h].y = x1;
      qy[h].x = y0; qy[h].y = y1;
      qz[h].x = z0; qz[h].y = z1;
      d[h].x = DEVINF; d[h].y = DEVINF;
      p4[i0] = float4{x0, y0, z0, 0.f};
      p4[i1] = float4{x1, y1, z1, 0.f};
    }
    __syncthreads();
    unsigned* p1u = (unsigned*)P.p1 + (size_t)b * 3072;
    int last = 0;
    for (int s = 0; s < 1024; ++s) {
      float4 c4 = p4[last];
      if (tid == 0) {
        if (s > 0) {
          asm volatile("s_waitcnt vmcnt(0)" ::: "memory");  // iter s-1 stores done
          __hip_atomic_store(P.prog + b, s, __ATOMIC_RELAXED, __HIP_MEMORY_SCOPE_AGENT);
        }
        __hip_atomic_store(p1u + 3 * s + 0, __float_as_uint(c4.x), __ATOMIC_RELAXED, __HIP_MEMORY_SCOPE_AGENT);
        __hip_atomic_store(p1u + 3 * s + 1, __float_as_uint(c4.y), __ATOMIC_RELAXED, __HIP_MEMORY_SCOPE_AGENT);
        __hip_atomic_store(p1u + 3 * s + 2, __float_as_uint(c4.z), __ATOMIC_RELAXED, __HIP_MEMORY_SCOPE_AGENT);
      }
      unsigned long long k =
          fps_wave_step<4, 4>(qx, qy, qz, d, c4.x, c4.y, c4.z, lane, ibase);
      if (lane == 63) kv[s & 1][w] = k;
      __syncthreads();
      unsigned long long k0 = kv[s & 1][0], k1 = kv[s & 1][1];
      unsigned long long k2 = kv[s & 1][2], k3 = kv[s & 1][3];
      unsigned long long ka = k0 > k1 ? k0 : k1;
      unsigned long long kb = k2 > k3 ? k2 : k3;
      unsigned long long kk = ka > kb ? ka : kb;
      last = (int)~(unsigned)kk;
    }
    if (tid == 0) {
      asm volatile("s_waitcnt vmcnt(0)" ::: "memory");
      __hip_atomic_store(P.prog + b, 1024, __ATOMIC_RELAXED, __HIP_MEMORY_SCOPE_AGENT);
    }
    return;
  }
  if (blockIdx.x < 32) {
    // ----------------------- fps2 (needs full p1) -----------------------
    const int bb = blockIdx.x - 16;
    float4* q4 = (float4*)lds;
    float4* carr = (float4*)(lds + 16384);
    unsigned long long(*kv2)[4] = (unsigned long long(*)[4])(lds + 20480);
    if (tid == 0) {
      while (__hip_atomic_load(P.prog + bb, __ATOMIC_RELAXED, __HIP_MEMORY_SCOPE_AGENT) < 1024)
        __builtin_amdgcn_s_sleep(64);
    }
    __syncthreads();
    __builtin_amdgcn_s_setprio(1);
    const unsigned* p1u = (const unsigned*)P.p1 + (size_t)bb * 3072;
    for (int i = tid; i < 1024; i += 256) {
      float xx = __uint_as_float(__hip_atomic_load(p1u + 3 * i + 0, __ATOMIC_RELAXED, __HIP_MEMORY_SCOPE_AGENT));
      float yy = __uint_as_float(__hip_atomic_load(p1u + 3 * i + 1, __ATOMIC_RELAXED, __HIP_MEMORY_SCOPE_AGENT));
      float zz = __uint_as_float(__hip_atomic_load(p1u + 3 * i + 2, __ATOMIC_RELAXED, __HIP_MEMORY_SCOPE_AGENT));
      q4[i] = float4{xx, yy, zz, 0.f};
    }
    __syncthreads();
    fps2_core(q4, carr, kv2, P.p2 + (size_t)bb * 768, tid, w, lane);
    return;
  }
  // ----------------------- sa1 consumer -----------------------
  const int cid = blockIdx.x - 32;
  for (int blk = cid; blk < P.nprep; blk += P.ncons)
    do_prep_chunk(P.jb, blk, tid);  // sa2/gsa weight prep: no intra-kernel consumer
  unsigned short* bufA_hi = (unsigned short*)lds;
  unsigned short* bufA_lo = (unsigned short*)(lds + 9216);
  unsigned short* bufB_hi = (unsigned short*)(lds + 18432);
  unsigned short* bufB_lo = (unsigned short*)(lds + 27648);
  int* nb = (int*)(lds + 36864);
  int* tot = (int*)(lds + 37120);
  int* sh_w = (int*)(lds + 37136);
  float* shc = (float*)(lds + 37140);
  const unsigned* p1u = (const unsigned*)P.p1;
  for (;;) {
    if (tid == 0) sh_w[0] = atomicAdd(P.wctr, 1);
    __syncthreads();
    int iw = sh_w[0];
    if (iw >= 16384) break;  // uniform
    int s = iw >> 4, b = iw & 15;  // center-major: matches production order
    if (tid == 0) {
      while (__hip_atomic_load(P.prog + b, __ATOMIC_RELAXED, __HIP_MEMORY_SCOPE_AGENT) <= s)
        __builtin_amdgcn_s_sleep(64);
      const unsigned* cp = p1u + (size_t)b * 3072 + 3 * s;
      shc[0] = __uint_as_float(__hip_atomic_load(cp + 0, __ATOMIC_RELAXED, __HIP_MEMORY_SCOPE_AGENT));
      shc[1] = __uint_as_float(__hip_atomic_load(cp + 1, __ATOMIC_RELAXED, __HIP_MEMORY_SCOPE_AGENT));
      shc[2] = __uint_as_float(__hip_atomic_load(cp + 2, __ATOMIC_RELAXED, __HIP_MEMORY_SCOPE_AGENT));
    }
    __syncthreads();
    sa1_body(b, b * 1024 + s, shc[0], shc[1], shc[2], P.x, P.pos, P.w1h, P.w1l,
             P.w2h, P.w2l, P.w3h, P.w3l, P.b1, P.b2, P.b3, P.x1, bufA_hi,
             bufA_lo, bufB_hi, bufB_lo, nb, tot);
    __syncthreads();  // protect LDS (sh_w/shc/bufs) reuse across items
  }
}

// ---------------------------------------------------------------------------
// SA2 (MFMA, wave=n-slice): register-mask ball query + MLP + maxpool.
// ---------------------------------------------------------------------------
__global__ __launch_bounds__(256, 2) void sa2_kernel(
    const float* __restrict__ x1,   // [16][1024][128]
    const float* __restrict__ pos1, // [16][1024][3]
    const float* __restrict__ ctr,  // [16][256][3]
    const unsigned short* __restrict__ w1h, const unsigned short* __restrict__ w1l,
    const unsigned short* __restrict__ w2h, const unsigned short* __restrict__ w2l,
    const unsigned short* __restrict__ w3h, const unsigned short* __restrict__ w3l,
    const float* __restrict__ b1, const float* __restrict__ b2,
    const float* __restrict__ b3,
    float* __restrict__ out)        // [16][256][256]
{
  const int N = 1024;
  const float r2 = (float)(0.4 * 0.4);
  const int bs = blockIdx.x;
  const int b = bs >> 8;
  const int tid = threadIdx.x;
  const int w = tid >> 6, lane = tid & 63;
  const float cx = ctr[bs * 3 + 0], cy = ctr[bs * 3 + 1], cz = ctr[bs * 3 + 2];
  __shared__ __align__(16) unsigned short bufA_hi[64 * 168], bufA_lo[64 * 168];
  __shared__ __align__(16) unsigned short bufB_hi[64 * 136], bufB_lo[64 * 136];
  __shared__ int nb[64];
  __shared__ int tot[4];
  nb[lane] = 0;
  unsigned long long mloc[4];
  {
#pragma clang fp contract(off)
#pragma unroll
    for (int it = 0; it < 4; ++it) {
      int i = (w * 4 + it) * 64 + lane;
      const float* p = pos1 + ((size_t)b * N + i) * 3;
      float dx = p[0] - cx, dy = p[1] - cy, dz = p[2] - cz;
      float t0 = dx * dx, t1 = dy * dy, t2 = dz * dz;
      float d2 = (t0 + t1) + t2;
      mloc[it] = __ballot(d2 <= r2);
    }
  }
  {
    int mytot = 0;
#pragma unroll
    for (int it = 0; it < 4; ++it) mytot += (int)__popcll(mloc[it]);
    if (lane == 0) tot[w] = mytot;
  }
  __syncthreads();
  const int t0s = tot[0], t1s = tot[1], t2s = tot[2], t3s = tot[3];
  {
    int cnt = (w > 0 ? t0s : 0) + (w > 1 ? t1s : 0) + (w > 2 ? t2s : 0);
#pragma unroll
    for (int it = 0; it < 4; ++it) {
      unsigned long long m = mloc[it];
      bool inr = (m >> lane) & 1;
      int posn = cnt + (int)__popcll(m & ((1ull << lane) - 1ull));
      if (inr && posn < 64) nb[posn] = (w * 4 + it) * 64 + lane;
      cnt += (int)__popcll(m);
    }
  }
  const int total = t0s + t1s + t2s + t3s;
  const int nvalid = total < 64 ? total : 64;
  __syncthreads();  // nb complete & visible
  {  // stage features: quarter w loads k in [32w, 32w+32); w0 also rel+pad
    int j = nb[lane];
    const float* xr = x1 + ((size_t)b * N + j) * 128 + 32 * w;
#pragma unroll
    for (int g = 0; g < 8; ++g) {
      float4 v = *(const float4*)(xr + 4 * g);
      float vv[4] = {v.x, v.y, v.z, v.w};
#pragma unroll
      for (int e = 0; e < 4; ++e) {
        unsigned short h, l;
        split_bf(vv[e], h, l);
        int k = 32 * w + 4 * g + e;
        bufA_hi[lane * 168 + k] = h;
        bufA_lo[lane * 168 + k] = l;
      }
    }
    if (w == 0) {
      const float* pr = pos1 + ((size_t)b * N + j) * 3;
      float rr[3] = {pr[0] - cx, pr[1] - cy, pr[2] - cz};
#pragma unroll
      for (int c = 0; c < 3; ++c) {
        unsigned short h, l;
        split_bf(rr[c], h, l);
        bufA_hi[lane * 168 + 128 + c] = h;
        bufA_lo[lane * 168 + 128 + c] = l;
      }
#pragma unroll
      for (int k = 131; k < 160; ++k) {
        bufA_hi[lane * 168 + k] = 0;
        bufA_lo[lane * 168 + k] = 0;
      }
    }
  }
  __syncthreads();
  {  // L1: K=160(131), N=128; n-slice [w*32, w*32+32)
    f32x4 acc[4][2];
    mfma_allm<5, 2>(bufA_hi, bufA_lo, 168, w1h, w1l, 168, b1, w * 32, lane, acc);
    store_allm<2>(acc, w * 32, bufB_hi, bufB_lo, 136, lane);
  }
  __syncthreads();
  {  // L2: K=128, N=128; reads B, writes A
    f32x4 acc[4][2];
    mfma_allm<4, 2>(bufB_hi, bufB_lo, 136, w2h, w2l, 136, b2, w * 32, lane, acc);
    store_allm<2>(acc, w * 32, bufA_hi, bufA_lo, 168, lane);
  }
  __syncthreads();
  {  // L3: K=128, N=256; n-slice [w*64, w*64+64) + pool
    f32x4 acc[4][4];
    mfma_allm<4, 4>(bufA_hi, bufA_lo, 168, w3h, w3l, 136, b3, w * 64, lane, acc);
    outpool_allm<4>(acc, w * 64, out + (size_t)bs * 256, nvalid, lane);
  }
}

// ---------------------------------------------------------------------------
// Global SA (MFMA): MLP 259->256->512->1024, 16 points/block, wave=n-quarter.
// ---------------------------------------------------------------------------
__global__ __launch_bounds__(256, 2) void gsa_kernel(
    const float* __restrict__ x2,  // [16][256][256]
    const float* __restrict__ p2,  // [16][256][3]
    const unsigned short* __restrict__ g1h, const unsigned short* __restrict__ g1l,
    const unsigned short* __restrict__ g2h, const unsigned short* __restrict__ g2l,
    const unsigned short* __restrict__ g3h, const unsigned short* __restrict__ g3l,
    const float* __restrict__ b1, const float* __restrict__ b2,
    const float* __restrict__ b3,
    float* __restrict__ part)      // [16][16][1024]
{
  const int blk = blockIdx.x;  // 256
  const int bt = blk >> 4, gidx = blk & 15;
  const int tid = threadIdx.x;
  const int w = tid >> 6, lane = tid & 63;
  const int p0 = gidx * 16;
  __shared__ __align__(16) unsigned short inH[16 * 296], inL[16 * 296];
  __shared__ __align__(16) unsigned short h1H[16 * 264], h1L[16 * 264];
  __shared__ __align__(16) unsigned short h2H[16 * 520], h2L[16 * 520];
  {  // stage 16 points x 256 feats + 3 pos + zero pad to 288
    int p = tid >> 4, seg = tid & 15;
    const float* xr = x2 + ((size_t)(bt * 256 + p0 + p)) * 256 + seg * 16;
#pragma unroll
    for (int g = 0; g < 4; ++g) {
      float4 v = *(const float4*)(xr + 4 * g);
      float vv[4] = {v.x, v.y, v.z, v.w};
#pragma unroll
      for (int e = 0; e < 4; ++e) {
        unsigned short h, l;
        split_bf(vv[e], h, l);
        int k = seg * 16 + 4 * g + e;
        inH[p * 296 + k] = h;
        inL[p * 296 + k] = l;
      }
    }
    if (tid < 16) {
      const float* pr = p2 + (bt * 256 + p0 + tid) * 3;
#pragma unroll
      for (int c = 0; c < 3; ++c) {
        unsigned short h, l;
        split_bf(pr[c], h, l);
        inH[tid * 296 + 256 + c] = h;
        inL[tid * 296 + 256 + c] = l;
      }
      for (int k = 259; k < 288; ++k) {
        inH[tid * 296 + k] = 0;
        inL[tid * 296 + k] = 0;
      }
    }
  }
  __syncthreads();
  {  // L1: K=288(259), N=256
    f32x4 acc[4];
    mfma_1m<9, 4>(inH, inL, 296, g1h, g1l, 296, b1, w * 64, lane, acc);
    store_1m<4>(acc, w * 64, h1H, h1L, 264, lane);
  }
  __syncthreads();
  {  // L2: K=256, N=512
    f32x4 acc[8];
    mfma_1m<8, 8>(h1H, h1L, 264, g2h, g2l, 264, b2, w * 128, lane, acc);
    store_1m<8>(acc, w * 128, h2H, h2L, 520, lane);
  }
  __syncthreads();
  {  // L3: K=512, N=1024 + max over 16 points
    f32x4 acc[16];
    mfma_1m<16, 16>(h2H, h2L, 520, g3h, g3l, 520, b3, w * 256, lane, acc);
    const int col = lane & 15;
    float* op = part + ((size_t)(bt * 16 + gidx)) * 1024 + w * 256;
#pragma unroll
    for (int t = 0; t < 16; ++t) {
      float m = -DEVINF;
#pragma unroll
      for (int r = 0; r < 4; ++r) m = fmaxf(m, fmaxf(acc[t][r], 0.f));
      m = fmaxf(m, __shfl_xor(m, 16, 64));
      m = fmaxf(m, __shfl_xor(m, 32, 64));
      if ((lane >> 4) == 0) op[t * 16 + col] = m;
    }
  }
}

// ---------------------------------------------------------------------------
// head1: gmax + l1 + l2 + l3. One block per B-row (16 blocks).
// ---------------------------------------------------------------------------
__global__ __launch_bounds__(256) void head1_kernel(
    const float* __restrict__ part,  // [16][16][1024]
    const float* __restrict__ l1w, const float* __restrict__ l1b,
    const float* __restrict__ l2w, const float* __restrict__ l2b,
    const float* __restrict__ l3w, const float* __restrict__ l3b,
    float* __restrict__ hC)          // [16][256]
{
  const int m = blockIdx.x;
  const int tid = threadIdx.x;
  __shared__ float gA[1024];
  __shared__ float hX[512];
  __shared__ float hY[256];
#pragma unroll
  for (int j = 0; j < 4; ++j) {
    int c = j * 256 + tid;
    float mx = -DEVINF;
#pragma unroll
    for (int t = 0; t < 16; ++t)
      mx = fmaxf(mx, part[((size_t)(m * 16 + t)) * 1024 + c]);
    gA[c] = mx;
  }
  __syncthreads();
  {  // l1: 1024 -> 512, relu
    float a0 = l1b[tid], a1 = l1b[tid + 256];
#pragma unroll 4
    for (int k = 0; k < 1024; ++k) {
      float v = gA[k];
      a0 = fmaf(v, l1w[(size_t)k * 512 + tid], a0);
      a1 = fmaf(v, l1w[(size_t)k * 512 + tid + 256], a1);
    }
    hX[tid] = fmaxf(a0, 0.f);
    hX[tid + 256] = fmaxf(a1, 0.f);
  }
  __syncthreads();
  {  // l2: 512 -> 256, relu
    float a = l2b[tid];
#pragma unroll 4
    for (int k = 0; k < 512; ++k) a = fmaf(hX[k], l2w[(size_t)k * 256 + tid], a);
    hY[tid] = fmaxf(a, 0.f);
  }
  __syncthreads();
  {  // l3: 256 -> 256, no relu
    float a = l3b[tid];
#pragma unroll 4
    for (int k = 0; k < 256; ++k) a = fmaf(hY[k], l3w[(size_t)k * 256 + tid], a);
    hC[(size_t)m * 256 + tid] = a;
  }
}

// ---------------------------------------------------------------------------
// head2: fusion MLP (fw1,fw2,fw3) + l4 + l5. One block per fused row (4).
// ---------------------------------------------------------------------------
__global__ __launch_bounds__(256) void head2_kernel(
    const float* __restrict__ hC,  // [4][1024]
    const float* __restrict__ fw1, const float* __restrict__ fb1,
    const float* __restrict__ fw2, const float* __restrict__ fb2,
    const float* __restrict__ fw3, const float* __restrict__ fb3,
    const float* __restrict__ l4w, const float* __restrict__ l4b,
    const float* __restrict__ l5w, const float* __restrict__ l5b,
    float* __restrict__ out)       // [4][128]
{
  const int m = blockIdx.x;
  const int tid = threadIdx.x;
  __shared__ float A[1024];
  __shared__ float Bf[512];
#pragma unroll
  for (int j = 0; j < 4; ++j) A[j * 256 + tid] = hC[(size_t)m * 1024 + j * 256 + tid];
  __syncthreads();
  {  // fw1: 1024 -> 512 relu, A -> Bf
    float a0 = fb1[tid], a1 = fb1[tid + 256];
#pragma unroll 4
    for (int k = 0; k < 1024; ++k) {
      float v = A[k];
      a0 = fmaf(v, fw1[(size_t)k * 512 + tid], a0);
      a1 = fmaf(v, fw1[(size_t)k * 512 + tid + 256], a1);
    }
    Bf[tid] = fmaxf(a0, 0.f);
    Bf[tid + 256] = fmaxf(a1, 0.f);
  }
  __syncthreads();
  {  // fw2: 512 -> 512 relu, Bf -> A
    float a0 = fb2[tid], a1 = fb2[tid + 256];
#pragma unroll 4
    for (int k = 0; k < 512; ++k) {
      float v = Bf[k];
      a0 = fmaf(v, fw2[(size_t)k * 512 + tid], a0);
      a1 = fmaf(v, fw2[(size_t)k * 512 + tid + 256], a1);
    }
    __syncthreads();
    A[tid] = fmaxf(a0, 0.f);
    A[tid + 256] = fmaxf(a1, 0.f);
  }
  __syncthreads();
  {  // fw3: 512 -> 256 relu, A -> Bf
    float a = fb3[tid];
#pragma unroll 4
    for (int k = 0; k < 512; ++k) a = fmaf(A[k], fw3[(size_t)k * 256 + tid], a);
    __syncthreads();
    Bf[tid] = fmaxf(a, 0.f);
  }
  __syncthreads();
  {  // l4: 256 -> 128 relu, Bf -> A
    if (tid < 128) {
      float a = l4b[tid];
#pragma unroll 4
      for (int k = 0; k < 256; ++k) a = fmaf(Bf[k], l4w[(size_t)k * 128 + tid], a);
      A[tid] = fmaxf(a, 0.f);
    }
  }
  __syncthreads();
  {  // l5: 128 -> 128, A -> out
    if (tid < 128) {
      float a = l5b[tid];
#pragma unroll 4
      for (int k = 0; k < 128; ++k) a = fmaf(A[k], l5w[(size_t)k * 128 + tid], a);
      out[(size_t)m * 128 + tid] = a;
    }
  }
}

// ---------------------------------------------------------------------------
extern "C" void kernel_launch(void* const* d_in, const int* in_sizes, int n_in,
                              void* d_out, int out_size, void* d_ws, size_t ws_size,
                              hipStream_t stream) {
  (void)in_sizes; (void)n_in; (void)out_size;
  const float* x    = (const float*)d_in[0];
  const float* pos  = (const float*)d_in[1];
  const float* s1w1 = (const float*)d_in[2];  const float* s1b1 = (const float*)d_in[3];
  const float* s1w2 = (const float*)d_in[4];  const float* s1b2 = (const float*)d_in[5];
  const float* s1w3 = (const float*)d_in[6];  const float* s1b3 = (const float*)d_in[7];
  const float* s2w1 = (const float*)d_in[8];  const float* s2b1 = (const float*)d_in[9];
  const float* s2w2 = (const float*)d_in[10]; const float* s2b2 = (const float*)d_in[11];
  const float* s2w3 = (const float*)d_in[12]; const float* s2b3 = (const float*)d_in[13];
  const float* s3w1 = (const float*)d_in[14]; const float* s3b1 = (const float*)d_in[15];
  const float* s3w2 = (const float*)d_in[16]; const float* s3b2 = (const float*)d_in[17];
  const float* s3w3 = (const float*)d_in[18]; const float* s3b3 = (const float*)d_in[19];
  const float* fw1  = (const float*)d_in[20]; const float* fb1  = (const float*)d_in[21];
  const float* fw2  = (const float*)d_in[22]; const float* fb2  = (const float*)d_in[23];
  const float* fw3  = (const float*)d_in[24]; const float* fb3  = (const float*)d_in[25];
  const float* l1w  = (const float*)d_in[26]; const float* l1b  = (const float*)d_in[27];
  const float* l2w  = (const float*)d_in[28]; const float* l2b  = (const float*)d_in[29];
  const float* l3w  = (const float*)d_in[30]; const float* l3b  = (const float*)d_in[31];
  const float* l4w  = (const float*)d_in[32]; const float* l4b  = (const float*)d_in[33];
  const float* l5w  = (const float*)d_in[34]; const float* l5b  = (const float*)d_in[35];
  float* out = (float*)d_out;

  float* ws = (float*)d_ws;
  float* p1   = ws;                  // 16*1024*3
  float* x1   = p1 + 49152;          // 16*1024*128
  float* p2   = x1 + 2097152;        // 16*256*3
  float* x2   = p2 + 12288;          // 16*256*256
  float* part = x2 + 1048576;        // 16*16*1024
  float* hC   = part + 262144;       // 16*256
  // bf16 hi/lo transposed weight planes (u16)
  unsigned short* wp = (unsigned short*)(hC + 4096);
  unsigned short* s1w1h = wp;              unsigned short* s1w1l = s1w1h + 2560;    // [64][40]
  unsigned short* s1w2h = s1w1l + 2560;    unsigned short* s1w2l = s1w2h + 4608;    // [64][72]
  unsigned short* s1w3h = s1w2l + 4608;    unsigned short* s1w3l = s1w3h + 9216;    // [128][72]
  unsigned short* s2w1h = s1w3l + 9216;    unsigned short* s2w1l = s2w1h + 21504;   // [128][168]
  unsigned short* s2w2h = s2w1l + 21504;   unsigned short* s2w2l = s2w2h + 17408;   // [128][136]
  unsigned short* s2w3h = s2w2l + 17408;   unsigned short* s2w3l = s2w3h + 34816;   // [256][136]
  unsigned short* g1h   = s2w3l + 34816;   unsigned short* g1l   = g1h + 75776;     // [256][296]
  unsigned short* g2h   = g1l + 75776;     unsigned short* g2l   = g2h + 135168;    // [512][264]
  unsigned short* g3h   = g2l + 135168;    unsigned short* g3l   = g3h + 532480;    // [1024][520]
  int* ctrl = (int*)(g3l + 532480);        // prog[16] + wctr (68 B)
  int* prog = ctrl;
  int* wctr = ctrl + 16;

  // jbA: s1 weights (needed by fused consumers -> pre-kernel)
  PrepJobs jbA{};
  {
    const float* s[3] = {s1w1, s1w2, s1w3};
    unsigned short* hs[3] = {s1w1h, s1w2h, s1w3h};
    unsigned short* ls[3] = {s1w1l, s1w2l, s1w3l};
    int Ks[3] = {12, 64, 64}, Ns[3] = {64, 64, 128}, rls[3] = {40, 72, 72};
    int acc = 0;
    for (int j = 0; j < 3; ++j) {
      jbA.src[j] = s[j]; jbA.hi[j] = hs[j]; jbA.lo[j] = ls[j];
      jbA.K[j] = Ks[j]; jbA.N[j] = Ns[j]; jbA.rl[j] = rls[j];
      jbA.blk0[j] = acc;
      acc += (Ns[j] * rls[j] + 255) / 256;
    }
    for (int j = 3; j < 9; ++j) jbA.blk0[j] = 0x7fffffff;
    jbA.blk0[9] = acc;  // 64
  }
  // jbB: sa2/gsa weights (done by fused consumers, or fallback prep kernel)
  PrepJobs jbB{};
  int accB = 0;
  {
    const float* s[6] = {s2w1, s2w2, s2w3, s3w1, s3w2, s3w3};
    unsigned short* hs[6] = {s2w1h, s2w2h, s2w3h, g1h, g2h, g3h};
    unsigned short* ls[6] = {s2w1l, s2w2l, s2w3l, g1l, g2l, g3l};
    int Ks[6] = {131, 128, 128, 259, 256, 512};
    int Ns[6] = {128, 128, 256, 256, 512, 1024};
    int rls[6] = {168, 136, 136, 296, 264, 520};
    for (int j = 0; j < 6; ++j) {
      jbB.src[j] = s[j]; jbB.hi[j] = hs[j]; jbB.lo[j] = ls[j];
      jbB.K[j] = Ks[j]; jbB.N[j] = Ns[j]; jbB.rl[j] = rls[j];
      jbB.blk0[j] = accB;
      accB += (Ns[j] * rls[j] + 255) / 256;
    }
    for (int j = 6; j < 9; ++j) jbB.blk0[j] = 0x7fffffff;
    jbB.blk0[9] = accB;  // 3192
  }

  // --- fused cooperative path (fps1 || sa1, fps2 tail), with safe fallback ---
  bool try_coop = (ws_size >= 17227844ull);  // layout end incl. ctrl block
  static int gblocks = -2;
  if (try_coop) {
    if (gblocks == -2) {
      int dev = 0;
      (void)hipGetDevice(&dev);
      int ncu = 0;
      (void)hipDeviceGetAttribute(&ncu, hipDeviceAttributeMultiprocessorCount, dev);
      int maxb = 0;
      (void)hipOccupancyMaxActiveBlocksPerMultiprocessor(&maxb, (const void*)fused_kernel, 256, 0);
      gblocks = (ncu > 0 && maxb > 0) ? ncu * maxb : -1;
    }
    if (gblocks < 64) try_coop = false;
  }
  bool coop_done = false;
  bool prepA_done = false;
  if (try_coop) {
    hipMemsetAsync(ctrl, 0, 68, stream);
    prep_kernel<<<64, 256, 0, stream>>>(jbA);
    prepA_done = true;
    FusedParams fp;
    fp.x = x; fp.pos = pos; fp.p1 = p1; fp.p2 = p2;
    fp.w1h = s1w1h; fp.w1l = s1w1l; fp.w2h = s1w2h; fp.w2l = s1w2l;
    fp.w3h = s1w3h; fp.w3l = s1w3l;
    fp.b1 = s1b1; fp.b2 = s1b2; fp.b3 = s1b3;
    fp.x1 = x1; fp.prog = prog; fp.wctr = wctr;
    fp.jb = jbB; fp.nprep = accB; fp.ncons = gblocks - 32;
    void* kargs[] = {(void*)&fp};
    hipError_t e = hipLaunchCooperativeKernel((const void*)fused_kernel,
                                              dim3((unsigned)gblocks), dim3(256),
                                              kargs, 0, stream);
    coop_done = (e == hipSuccess);
  }
  if (!coop_done) {
    if (!prepA_done) prep_kernel<<<64, 256, 0, stream>>>(jbA);
    prep_kernel<<<accB, 256, 0, stream>>>(jbB);
    fps1_kernel<<<16, 256, 0, stream>>>(pos, p1);
    sa1_kernel<<<16 * 1024 + 16, 256, 0, stream>>>(x, pos, p1, p2, s1w1h, s1w1l,
                                                   s1w2h, s1w2l, s1w3h, s1w3l,
                                                   s1b1, s1b2, s1b3, x1);
  }
  sa2_kernel<<<16 * 256, 256, 0, stream>>>(x1, p1, p2, s2w1h, s2w1l, s2w2h,
                                           s2w2l, s2w3h, s2w3l, s2b1, s2b2,
                                           s2b3, x2);
  gsa_kernel<<<256, 256, 0, stream>>>(x2, p2, g1h, g1l, g2h, g2l, g3h, g3l,
                                      s3b1, s3b2, s3b3, part);
  head1_kernel<<<16, 256, 0, stream>>>(part, l1w, l1b, l2w, l2b, l3w, l3b, hC);
  head2_kernel<<<4, 256, 0, stream>>>(hC, fw1, fb1, fw2, fb2, fw3, fb3, l4w,
                                      l4b, l5w, l5b, out);
}

// Round 7
// 1454.311 us; speedup vs baseline: 2.2815x; 2.2815x over previous
//
#include <hip/hip_runtime.h>
#include <cstddef>

#define DEVINF __builtin_inff()

typedef __attribute__((ext_vector_type(8))) short bf16x8;
typedef __attribute__((ext_vector_type(4))) float f32x4;
typedef __attribute__((ext_vector_type(2))) float f32x2;

#define PROG_STRIDE 32  // ints; pads each prog flag to its own 128B line

__device__ __forceinline__ unsigned short f2bf(float x) {
  unsigned u = __float_as_uint(x);
  return (unsigned short)((u + 0x7fff + ((u >> 16) & 1)) >> 16);
}
__device__ __forceinline__ float bf2f(unsigned short h) {
  return __uint_as_float(((unsigned)h) << 16);
}
__device__ __forceinline__ void split_bf(float x, unsigned short& hi, unsigned short& lo) {
  hi = f2bf(x);
  lo = f2bf(x - bf2f(hi));
}

// physical CU identity: CU/SH/SE bits of HW_ID + XCC_ID (perf heuristic only)
__device__ __forceinline__ unsigned read_cu_id() {
  unsigned hwid, xcc;
  asm volatile("s_getreg_b32 %0, hwreg(HW_REG_HW_ID, 0, 32)" : "=s"(hwid));
  asm volatile("s_getreg_b32 %0, hwreg(HW_REG_XCC_ID, 0, 32)" : "=s"(xcc));
  return (hwid & 0xFF00u) | ((xcc & 0xFFu) << 16);
}

// ---------------------------------------------------------------------------
// FPS cooperative step (round-0 proven form): per-wave update, DPP ladder to
// lane 63. Key = (val_bits<<32)|~idx -> (max value, min index), exact u32
// compare, order-independent.
// ---------------------------------------------------------------------------
#define FPS_RED_LEVEL(CTRL)                                                      \
  {                                                                              \
    int th = __builtin_amdgcn_update_dpp((int)hi, (int)hi, CTRL, 0xf, 0xf, false); \
    int tl = __builtin_amdgcn_update_dpp((int)lo, (int)lo, CTRL, 0xf, 0xf, false); \
    bool take = ((unsigned)th > hi) || (((unsigned)th == hi) && ((unsigned)tl > lo)); \
    hi = take ? (unsigned)th : hi;                                               \
    lo = take ? (unsigned)tl : lo;                                               \
  }

template <int PPLH, int NCH>
__device__ __forceinline__ unsigned long long fps_wave_step(
    f32x2* qx, f32x2* qy, f32x2* qz, f32x2* d, float lx, float ly, float lz,
    int lane, int ibase) {
#pragma clang fp contract(off)
  const int CH = PPLH / NCH;
  float bv[NCH];
  int bi[NCH];
#pragma unroll
  for (int c = 0; c < NCH; ++c) { bv[c] = -DEVINF; bi[c] = 0x7fffffff; }
  f32x2 lxv = {lx, lx}, lyv = {ly, ly}, lzv = {lz, lz};
#pragma unroll
  for (int h = 0; h < PPLH; ++h) {
    const int c = h / CH;
    f32x2 dx = qx[h] - lxv, dy = qy[h] - lyv, dz = qz[h] - lzv;
    f32x2 t0 = dx * dx, t1 = dy * dy, t2 = dz * dz;
    f32x2 d2 = (t0 + t1) + t2;
    f32x2 dn;
    dn.x = fminf(d[h].x, d2.x);
    dn.y = fminf(d[h].y, d2.y);
    d[h] = dn;
    int i0 = ibase + (2 * h) * 64 + lane;
    if (dn.x > bv[c]) { bv[c] = dn.x; bi[c] = i0; }
    if (dn.y > bv[c]) { bv[c] = dn.y; bi[c] = i0 + 64; }
  }
  unsigned hi, lo;
  if (NCH == 4) {
    unsigned h0 = __float_as_uint(bv[0]), l0 = ~(unsigned)bi[0];
    unsigned h1 = __float_as_uint(bv[1]), l1 = ~(unsigned)bi[1];
    unsigned h2 = __float_as_uint(bv[2]), l2 = ~(unsigned)bi[2];
    unsigned h3 = __float_as_uint(bv[3]), l3 = ~(unsigned)bi[3];
    bool t01 = (h1 > h0) || ((h1 == h0) && (l1 > l0));
    unsigned ha = t01 ? h1 : h0, la = t01 ? l1 : l0;
    bool t23 = (h3 > h2) || ((h3 == h2) && (l3 > l2));
    unsigned hb = t23 ? h3 : h2, lb = t23 ? l3 : l2;
    bool tab = (hb > ha) || ((hb == ha) && (lb > la));
    hi = tab ? hb : ha;
    lo = tab ? lb : la;
  } else {
    const int c1 = (NCH > 1) ? 1 : 0;
    unsigned h0 = __float_as_uint(bv[0]), l0 = ~(unsigned)bi[0];
    unsigned h1 = __float_as_uint(bv[c1]), l1 = ~(unsigned)bi[c1];
    bool t01 = (h1 > h0) || ((h1 == h0) && (l1 > l0));
    hi = t01 ? h1 : h0;
    lo = t01 ? l1 : l0;
  }
  FPS_RED_LEVEL(0x111)  // row_shr:1
  FPS_RED_LEVEL(0x112)  // row_shr:2
  FPS_RED_LEVEL(0x114)  // row_shr:4
  FPS_RED_LEVEL(0x118)  // row_shr:8
  FPS_RED_LEVEL(0x142)  // row_bcast:15
  FPS_RED_LEVEL(0x143)  // row_bcast:31
  return (((unsigned long long)hi) << 32) | lo;  // valid on lane 63
}

// ---------------------------------------------------------------------------
// prep jobs (bf16 hi/lo transposed weight planes). Unused slots: blk0 = INT_MAX.
// ---------------------------------------------------------------------------
struct PrepJobs {
  const float* src[9];
  unsigned short* hi[9];
  unsigned short* lo[9];
  int K[9], N[9], rl[9];
  int blk0[10];
};

__device__ __forceinline__ void do_prep_chunk(const PrepJobs& jb, int blk, int tid) {
  int j = 0;
#pragma unroll
  for (int t = 1; t < 9; ++t)
    if (blk >= jb.blk0[t]) j = t;
  int idx = (blk - jb.blk0[j]) * 256 + tid;
  int rl = jb.rl[j], N = jb.N[j], K = jb.K[j];
  if (idx >= N * rl) return;
  int n = idx / rl, k = idx - n * rl;
  float v = (k < K) ? jb.src[j][(size_t)k * N + n] : 0.f;
  unsigned short h, l;
  split_bf(v, h, l);
  jb.hi[j][idx] = h;
  jb.lo[j][idx] = l;
}

__global__ __launch_bounds__(256) void prep_kernel(PrepJobs jb) {
  do_prep_chunk(jb, (int)blockIdx.x, (int)threadIdx.x);
}

// ---------------------------------------------------------------------------
// legacy fps1 (fallback path): 2048 -> 1024 centers, R0 4-wave barrier form.
// ---------------------------------------------------------------------------
__global__ __launch_bounds__(256, 1) void fps1_kernel(
    const float* __restrict__ pos, float* __restrict__ p1) {
#pragma clang fp contract(off)
  const int tid = threadIdx.x;
  const int b = blockIdx.x;
  const int w = tid >> 6, lane = tid & 63;
  __shared__ __align__(16) float4 p4[2048];
  __shared__ __align__(16) float4 carr[1024];
  __shared__ __align__(16) unsigned long long kv[2][4];
  f32x2 qx[4], qy[4], qz[4], d[4];
  const int ibase = w * 512;
#pragma unroll
  for (int h = 0; h < 4; ++h) {
    int i0 = ibase + (2 * h) * 64 + lane, i1 = i0 + 64;
    const float* a = pos + ((size_t)b * 2048 + i0) * 3;
    const float* c = pos + ((size_t)b * 2048 + i1) * 3;
    float x0 = a[0], y0 = a[1], z0 = a[2];
    float x1 = c[0], y1 = c[1], z1 = c[2];
    qx[h].x = x0; qx[h].y = x1;
    qy[h].x = y0; qy[h].y = y1;
    qz[h].x = z0; qz[h].y = z1;
    d[h].x = DEVINF; d[h].y = DEVINF;
    p4[i0] = float4{x0, y0, z0, 0.f};
    p4[i1] = float4{x1, y1, z1, 0.f};
  }
  __syncthreads();
  int last = 0;
  for (int s = 0; s < 1024; ++s) {
    float4 c4 = p4[last];
    if (tid == 0) carr[s] = c4;
    unsigned long long k =
        fps_wave_step<4, 4>(qx, qy, qz, d, c4.x, c4.y, c4.z, lane, ibase);
    if (lane == 63) kv[s & 1][w] = k;
    __syncthreads();
    unsigned long long k0 = kv[s & 1][0], k1 = kv[s & 1][1];
    unsigned long long k2 = kv[s & 1][2], k3 = kv[s & 1][3];
    unsigned long long ka = k0 > k1 ? k0 : k1;
    unsigned long long kb = k2 > k3 ? k2 : k3;
    unsigned long long kk = ka > kb ? ka : kb;
    last = (int)~(unsigned)kk;
  }
  for (int i = tid; i < 1024; i += 256) {
    float4 c = carr[i];
    p1[((size_t)b * 1024 + i) * 3 + 0] = c.x;
    p1[((size_t)b * 1024 + i) * 3 + 1] = c.y;
    p1[((size_t)b * 1024 + i) * 3 + 2] = c.z;
  }
}

// ---------------------------------------------------------------------------
// fps2 core (R0 barrier form): q4 pre-staged by caller; fills carr, writes p2.
// ---------------------------------------------------------------------------
__device__ __forceinline__ void fps2_core(float4* q4, float4* carr,
                                          unsigned long long (*kv2)[4],
                                          float* __restrict__ p2b, int tid,
                                          int w, int lane) {
#pragma clang fp contract(off)
  f32x2 qx[2], qy[2], qz[2], d[2];
  const int ibase = w * 256;
#pragma unroll
  for (int h = 0; h < 2; ++h) {
    int i0 = ibase + (2 * h) * 64 + lane, i1 = i0 + 64;
    float4 a = q4[i0], c = q4[i1];
    qx[h].x = a.x; qx[h].y = c.x;
    qy[h].x = a.y; qy[h].y = c.y;
    qz[h].x = a.z; qz[h].y = c.z;
    d[h].x = DEVINF; d[h].y = DEVINF;
  }
  int last = 0;
  for (int s = 0; s < 256; ++s) {
    float4 c4 = q4[last];
    if (tid == 0) carr[s] = c4;
    unsigned long long k =
        fps_wave_step<2, 2>(qx, qy, qz, d, c4.x, c4.y, c4.z, lane, ibase);
    if (lane == 63) kv2[s & 1][w] = k;
    __syncthreads();
    unsigned long long k0 = kv2[s & 1][0], k1 = kv2[s & 1][1];
    unsigned long long k2 = kv2[s & 1][2], k3 = kv2[s & 1][3];
    unsigned long long ka = k0 > k1 ? k0 : k1;
    unsigned long long kb = k2 > k3 ? k2 : k3;
    unsigned long long kk = ka > kb ? ka : kb;
    last = (int)~(unsigned)kk;
  }
  {
    float4 c = carr[tid];
    if (tid < 256) {
      p2b[3 * tid + 0] = c.x;
      p2b[3 * tid + 1] = c.y;
      p2b[3 * tid + 2] = c.z;
    }
  }
}

// ---------------------------------------------------------------------------
// MFMA building blocks — B fragments SOFTWARE-PIPELINED one (ks,t) step ahead.
// ---------------------------------------------------------------------------
template <int KS, int T>
__device__ __forceinline__ void mfma_allm(
    const unsigned short* __restrict__ inHi, const unsigned short* __restrict__ inLo,
    int sIn, const unsigned short* __restrict__ wHi,
    const unsigned short* __restrict__ wLo, int rl, const float* __restrict__ bias,
    int n0, int lane, f32x4 acc[4][T]) {
  const int col = lane & 15, quad = lane >> 4;
#pragma unroll
  for (int t = 0; t < T; ++t) {
    float bv = bias[n0 + t * 16 + col];
#pragma unroll
    for (int mt = 0; mt < 4; ++mt) {
      acc[mt][t].x = bv; acc[mt][t].y = bv; acc[mt][t].z = bv; acc[mt][t].w = bv;
    }
  }
  size_t b0 = (size_t)(n0 + col) * rl + quad * 8;
  bf16x8 bh = *(const bf16x8*)(wHi + b0);
  bf16x8 bl = *(const bf16x8*)(wLo + b0);
#pragma unroll 1
  for (int ks = 0; ks < KS; ++ks) {
    bf16x8 ah[4], al[4];
#pragma unroll
    for (int mt = 0; mt < 4; ++mt) {
      int aoff = (mt * 16 + col) * sIn + ks * 32 + quad * 8;
      ah[mt] = *(const bf16x8*)(inHi + aoff);
      al[mt] = *(const bf16x8*)(inLo + aoff);
    }
#pragma unroll
    for (int t = 0; t < T; ++t) {
      int nks = (t + 1 < T) ? ks : ks + 1;
      int nt = (t + 1 < T) ? t + 1 : 0;
      if (nks > KS - 1) nks = KS - 1;  // clamp: value unused on last step
      size_t nboff = (size_t)(n0 + nt * 16 + col) * rl + nks * 32 + quad * 8;
      bf16x8 nh = *(const bf16x8*)(wHi + nboff);
      bf16x8 nl = *(const bf16x8*)(wLo + nboff);
#pragma unroll
      for (int mt = 0; mt < 4; ++mt) {
        acc[mt][t] = __builtin_amdgcn_mfma_f32_16x16x32_bf16(ah[mt], bh, acc[mt][t], 0, 0, 0);
        acc[mt][t] = __builtin_amdgcn_mfma_f32_16x16x32_bf16(ah[mt], bl, acc[mt][t], 0, 0, 0);
        acc[mt][t] = __builtin_amdgcn_mfma_f32_16x16x32_bf16(al[mt], bh, acc[mt][t], 0, 0, 0);
      }
      bh = nh;
      bl = nl;
    }
  }
}

template <int T>
__device__ __forceinline__ void store_allm(const f32x4 acc[4][T], int n0,
                                           unsigned short* outHi,
                                           unsigned short* outLo, int sOut,
                                           int lane) {
  const int col = lane & 15, quad = lane >> 4;
#pragma unroll
  for (int mt = 0; mt < 4; ++mt)
#pragma unroll
    for (int t = 0; t < T; ++t)
#pragma unroll
      for (int r = 0; r < 4; ++r) {
        int edge = mt * 16 + quad * 4 + r;
        float v = fmaxf(acc[mt][t][r], 0.f);
        unsigned short h, l;
        split_bf(v, h, l);
        outHi[edge * sOut + n0 + t * 16 + col] = h;
        outLo[edge * sOut + n0 + t * 16 + col] = l;
      }
}

template <int T>
__device__ __forceinline__ void outpool_allm(const f32x4 acc[4][T], int n0,
                                             float* __restrict__ outp, int nvalid,
                                             int lane) {
  const int col = lane & 15, quad = lane >> 4;
#pragma unroll
  for (int t = 0; t < T; ++t) {
    float m = -DEVINF;
#pragma unroll
    for (int mt = 0; mt < 4; ++mt)
#pragma unroll
      for (int r = 0; r < 4; ++r) {
        int edge = mt * 16 + quad * 4 + r;
        float v = fmaxf(acc[mt][t][r], 0.f);
        if (edge >= nvalid) v = -DEVINF;
        m = fmaxf(m, v);
      }
    m = fmaxf(m, __shfl_xor(m, 16, 64));
    m = fmaxf(m, __shfl_xor(m, 32, 64));
    if (quad == 0) outp[n0 + t * 16 + col] = m;
  }
}

// single-m-tile variants (gsa), B-pipelined identically
template <int KS, int T>
__device__ __forceinline__ void mfma_1m(
    const unsigned short* __restrict__ inHi, const unsigned short* __restrict__ inLo,
    int sIn, const unsigned short* __restrict__ wHi,
    const unsigned short* __restrict__ wLo, int rl, const float* __restrict__ bias,
    int n0, int lane, f32x4 acc[T]) {
  const int col = lane & 15, quad = lane >> 4;
#pragma unroll
  for (int t = 0; t < T; ++t) {
    float bv = bias[n0 + t * 16 + col];
    acc[t].x = bv; acc[t].y = bv; acc[t].z = bv; acc[t].w = bv;
  }
  size_t b0 = (size_t)(n0 + col) * rl + quad * 8;
  bf16x8 bh = *(const bf16x8*)(wHi + b0);
  bf16x8 bl = *(const bf16x8*)(wLo + b0);
#pragma unroll 1
  for (int ks = 0; ks < KS; ++ks) {
    int aoff = col * sIn + ks * 32 + quad * 8;
    bf16x8 ah = *(const bf16x8*)(inHi + aoff);
    bf16x8 al = *(const bf16x8*)(inLo + aoff);
#pragma unroll
    for (int t = 0; t < T; ++t) {
      int nks = (t + 1 < T) ? ks : ks + 1;
      int nt = (t + 1 < T) ? t + 1 : 0;
      if (nks > KS - 1) nks = KS - 1;
      size_t nboff = (size_t)(n0 + nt * 16 + col) * rl + nks * 32 + quad * 8;
      bf16x8 nh = *(const bf16x8*)(wHi + nboff);
      bf16x8 nl = *(const bf16x8*)(wLo + nboff);
      acc[t] = __builtin_amdgcn_mfma_f32_16x16x32_bf16(ah, bh, acc[t], 0, 0, 0);
      acc[t] = __builtin_amdgcn_mfma_f32_16x16x32_bf16(ah, bl, acc[t], 0, 0, 0);
      acc[t] = __builtin_amdgcn_mfma_f32_16x16x32_bf16(al, bh, acc[t], 0, 0, 0);
      bh = nh;
      bl = nl;
    }
  }
}

template <int T>
__device__ __forceinline__ void store_1m(const f32x4 acc[T], int n0,
                                         unsigned short* outHi,
                                         unsigned short* outLo, int sOut, int lane) {
  const int col = lane & 15, quad = lane >> 4;
#pragma unroll
  for (int t = 0; t < T; ++t)
#pragma unroll
    for (int r = 0; r < 4; ++r) {
      int p = quad * 4 + r;
      float v = fmaxf(acc[t][r], 0.f);
      unsigned short h, l;
      split_bf(v, h, l);
      outHi[p * sOut + n0 + t * 16 + col] = h;
      outLo[p * sOut + n0 + t * 16 + col] = l;
    }
}

// ---------------------------------------------------------------------------
// SA1 body (R0-proven): ball query + staging + 3-layer MFMA MLP + maxpool.
// ---------------------------------------------------------------------------
__device__ __forceinline__ void sa1_body(
    int b, int bs, float cx, float cy, float cz,
    const float* __restrict__ x, const float* __restrict__ pos,
    const unsigned short* __restrict__ w1h, const unsigned short* __restrict__ w1l,
    const unsigned short* __restrict__ w2h, const unsigned short* __restrict__ w2l,
    const unsigned short* __restrict__ w3h, const unsigned short* __restrict__ w3l,
    const float* __restrict__ b1, const float* __restrict__ b2,
    const float* __restrict__ b3, float* __restrict__ out,
    unsigned short* bufA_hi, unsigned short* bufA_lo,
    unsigned short* bufB_hi, unsigned short* bufB_lo, int* nb, int* tot) {
  const int N = 2048;
  const float r2 = (float)(0.2 * 0.2);
  const int tid = threadIdx.x;
  const int w = tid >> 6, lane = tid & 63;
  nb[lane] = 0;
  unsigned long long mloc[8];
  {
#pragma clang fp contract(off)
#pragma unroll
    for (int it = 0; it < 8; ++it) {
      int i = (w * 8 + it) * 64 + lane;
      const float* p = pos + ((size_t)b * N + i) * 3;
      float dx = p[0] - cx, dy = p[1] - cy, dz = p[2] - cz;
      float t0 = dx * dx, t1 = dy * dy, t2 = dz * dz;
      float d2 = (t0 + t1) + t2;
      mloc[it] = __ballot(d2 <= r2);
    }
  }
  {
    int mytot = 0;
#pragma unroll
    for (int it = 0; it < 8; ++it) mytot += (int)__popcll(mloc[it]);
    if (lane == 0) tot[w] = mytot;
  }
  __syncthreads();
  const int t0s = tot[0], t1s = tot[1], t2s = tot[2], t3s = tot[3];
  {
    int cnt = (w > 0 ? t0s : 0) + (w > 1 ? t1s : 0) + (w > 2 ? t2s : 0);
#pragma unroll
    for (int it = 0; it < 8; ++it) {
      unsigned long long m = mloc[it];
      bool inr = (m >> lane) & 1;
      int posn = cnt + (int)__popcll(m & ((1ull << lane) - 1ull));
      if (inr && posn < 64) nb[posn] = (w * 8 + it) * 64 + lane;
      cnt += (int)__popcll(m);
    }
  }
  const int total = t0s + t1s + t2s + t3s;
  const int nvalid = total < 64 ? total : 64;
  __syncthreads();  // nb complete & visible
  {
    int j = nb[lane];
    if (w < 3) {
      const float* xr = x + ((size_t)b * N + j) * 9 + w * 3;
      float f0 = xr[0], f1 = xr[1], f2 = xr[2];
      unsigned short h, l;
      split_bf(f0, h, l); bufA_hi[lane * 72 + w * 3 + 0] = h; bufA_lo[lane * 72 + w * 3 + 0] = l;
      split_bf(f1, h, l); bufA_hi[lane * 72 + w * 3 + 1] = h; bufA_lo[lane * 72 + w * 3 + 1] = l;
      split_bf(f2, h, l); bufA_hi[lane * 72 + w * 3 + 2] = h; bufA_lo[lane * 72 + w * 3 + 2] = l;
    } else {
      const float* pr = pos + ((size_t)b * N + j) * 3;
      float rr[3] = {pr[0] - cx, pr[1] - cy, pr[2] - cz};
#pragma unroll
      for (int c = 0; c < 3; ++c) {
        unsigned short h, l;
        split_bf(rr[c], h, l);
        bufA_hi[lane * 72 + 9 + c] = h;
        bufA_lo[lane * 72 + 9 + c] = l;
      }
#pragma unroll
      for (int k = 12; k < 32; ++k) {
        bufA_hi[lane * 72 + k] = 0;
        bufA_lo[lane * 72 + k] = 0;
      }
    }
  }
  __syncthreads();
  {  // L1: K=32(12), N=64; wave n-slice [w*16, w*16+16)
    f32x4 acc[4][1];
    mfma_allm<1, 1>(bufA_hi, bufA_lo, 72, w1h, w1l, 40, b1, w * 16, lane, acc);
    store_allm<1>(acc, w * 16, bufB_hi, bufB_lo, 72, lane);
  }
  __syncthreads();
  {  // L2: K=64, N=64; reads B, writes A
    f32x4 acc[4][1];
    mfma_allm<2, 1>(bufB_hi, bufB_lo, 72, w2h, w2l, 72, b2, w * 16, lane, acc);
    store_allm<1>(acc, w * 16, bufA_hi, bufA_lo, 72, lane);
  }
  __syncthreads();
  {  // L3: K=64, N=128; wave n-slice [w*32, w*32+32) + pool
    f32x4 acc[4][2];
    mfma_allm<2, 2>(bufA_hi, bufA_lo, 72, w3h, w3l, 72, b3, w * 32, lane, acc);
    outpool_allm<2>(acc, w * 32, out + (size_t)bs * 128, nvalid, lane);
  }
}

// ---------------------------------------------------------------------------
// legacy sa1 (fallback): blocks 0..15 fps2, rest sa1_body with plain ctr reads.
// ---------------------------------------------------------------------------
__global__ __launch_bounds__(256, 4) void sa1_kernel(
    const float* __restrict__ x, const float* __restrict__ pos,
    const float* __restrict__ ctr, float* __restrict__ p2,
    const unsigned short* __restrict__ w1h, const unsigned short* __restrict__ w1l,
    const unsigned short* __restrict__ w2h, const unsigned short* __restrict__ w2l,
    const unsigned short* __restrict__ w3h, const unsigned short* __restrict__ w3l,
    const float* __restrict__ b1, const float* __restrict__ b2,
    const float* __restrict__ b3, float* __restrict__ out) {
  const int tid = threadIdx.x;
  const int w = tid >> 6, lane = tid & 63;
  __shared__ __align__(16) unsigned short smem[4 * 4608];
  __shared__ int nb[64];
  __shared__ int tot[4];
  __shared__ __align__(16) unsigned long long kv2s[2][4];
  if (blockIdx.x < 16) {
    const int bb = blockIdx.x;
    float4* q4 = (float4*)smem;
    float4* carr = (float4*)(smem + 8192);
    for (int i = tid; i < 1024; i += 256) {
      const float* pr = ctr + ((size_t)bb * 1024 + i) * 3;
      q4[i] = float4{pr[0], pr[1], pr[2], 0.f};
    }
    __syncthreads();
    fps2_core(q4, carr, kv2s, p2 + (size_t)bb * 768, tid, w, lane);
    return;
  }
  const int bs = blockIdx.x - 16;
  const int b = bs >> 10;
  const float cx = ctr[bs * 3 + 0], cy = ctr[bs * 3 + 1], cz = ctr[bs * 3 + 2];
  sa1_body(b, bs, cx, cy, cz, x, pos, w1h, w1l, w2h, w2l, w3h, w3l, b1, b2, b3,
           out, smem, smem + 4608, smem + 9216, smem + 13824, nb, tot);
}

// ---------------------------------------------------------------------------
// FUSED cooperative kernel with PRODUCER-CU ISOLATION:
//  - blocks 0..15: fps1 producers. Publish their physical CU id, then run the
//    R0 fps1 body, publishing centers progressively (agent-scope atomics;
//    prog flag padded to its own cache line, advanced after a 1-iter-lagged
//    s_waitcnt vmcnt(0) so the wait is ~free).
//  - blocks 16..31: fps2, waits for full p1.
//  - blocks 32..: consumers. Do weight-prep chunks, then EXIT if co-resident
//    with a producer CU (isolation — the R6 lesson: consumers on producer CUs
//    stretched the serial FPS chain 4.5x). Otherwise pull sa1 work items in
//    production order.
// ---------------------------------------------------------------------------
struct FusedParams {
  const float* x; const float* pos; float* p1; float* p2;
  const unsigned short *w1h, *w1l, *w2h, *w2l, *w3h, *w3l;
  const float *b1, *b2, *b3;
  float* x1;
  int* prog;    // [16 * PROG_STRIDE], padded
  int* wctr;
  int* pcuid;   // [16] producer CU ids
  int* pubcnt;  // count of published producer ids
  PrepJobs jb;  // jobs for sa2/gsa weights (6 used)
  int nprep;
  int ncons;
};

__global__ __launch_bounds__(256, 4) void fused_kernel(FusedParams P) {
  const int tid = threadIdx.x;
  const int w = tid >> 6, lane = tid & 63;
  __shared__ __align__(16) char lds[37184];
  if (blockIdx.x < 16) {
    // ----------------------- fps1 producer -----------------------
#pragma clang fp contract(off)
    const int b = blockIdx.x;
    if (tid == 0) {
      unsigned mycu = read_cu_id();
      __hip_atomic_store(P.pcuid + b, (int)mycu, __ATOMIC_RELAXED, __HIP_MEMORY_SCOPE_AGENT);
      __hip_atomic_fetch_add(P.pubcnt, 1, __ATOMIC_RELEASE, __HIP_MEMORY_SCOPE_AGENT);
    }
    __builtin_amdgcn_s_setprio(3);
    float4* p4 = (float4*)lds;
    unsigned long long(*kv)[4] = (unsigned long long(*)[4])(lds + 32768);
    f32x2 qx[4], qy[4], qz[4], d[4];
    const int ibase = w * 512;
#pragma unroll
    for (int h = 0; h < 4; ++h) {
      int i0 = ibase + (2 * h) * 64 + lane, i1 = i0 + 64;
      const float* a = P.pos + ((size_t)b * 2048 + i0) * 3;
      const float* c = P.pos + ((size_t)b * 2048 + i1) * 3;
      float x0 = a[0], y0 = a[1], z0 = a[2];
      float x1 = c[0], y1 = c[1], z1 = c[2];
      qx[h].x = x0; qx[h].y = x1;
      qy[h].x = y0; qy[h].y = y1;
      qz[h].x = z0; qz[h].y = z1;
      d[h].x = DEVINF; d[h].y = DEVINF;
      p4[i0] = float4{x0, y0, z0, 0.f};
      p4[i1] = float4{x1, y1, z1, 0.f};
    }
    __syncthreads();
    unsigned* p1u = (unsigned*)P.p1 + (size_t)b * 3072;
    int* progb = P.prog + b * PROG_STRIDE;
    int last = 0;
    for (int s = 0; s < 1024; ++s) {
      float4 c4 = p4[last];
      if (tid == 0) {
        if (s > 0) {
          asm volatile("s_waitcnt vmcnt(0)" ::: "memory");  // iter s-1 stores done
          __hip_atomic_store(progb, s, __ATOMIC_RELAXED, __HIP_MEMORY_SCOPE_AGENT);
        }
        __hip_atomic_store(p1u + 3 * s + 0, __float_as_uint(c4.x), __ATOMIC_RELAXED, __HIP_MEMORY_SCOPE_AGENT);
        __hip_atomic_store(p1u + 3 * s + 1, __float_as_uint(c4.y), __ATOMIC_RELAXED, __HIP_MEMORY_SCOPE_AGENT);
        __hip_atomic_store(p1u + 3 * s + 2, __float_as_uint(c4.z), __ATOMIC_RELAXED, __HIP_MEMORY_SCOPE_AGENT);
      }
      unsigned long long k =
          fps_wave_step<4, 4>(qx, qy, qz, d, c4.x, c4.y, c4.z, lane, ibase);
      if (lane == 63) kv[s & 1][w] = k;
      __syncthreads();
      unsigned long long k0 = kv[s & 1][0], k1 = kv[s & 1][1];
      unsigned long long k2 = kv[s & 1][2], k3 = kv[s & 1][3];
      unsigned long long ka = k0 > k1 ? k0 : k1;
      unsigned long long kb = k2 > k3 ? k2 : k3;
      unsigned long long kk = ka > kb ? ka : kb;
      last = (int)~(unsigned)kk;
    }
    if (tid == 0) {
      asm volatile("s_waitcnt vmcnt(0)" ::: "memory");
      __hip_atomic_store(progb, 1024, __ATOMIC_RELAXED, __HIP_MEMORY_SCOPE_AGENT);
    }
    return;
  }
  if (blockIdx.x < 32) {
    // ----------------------- fps2 (needs full p1) -----------------------
    const int bb = blockIdx.x - 16;
    float4* q4 = (float4*)lds;
    float4* carr = (float4*)(lds + 16384);
    unsigned long long(*kv2)[4] = (unsigned long long(*)[4])(lds + 20480);
    if (tid == 0) {
      while (__hip_atomic_load(P.prog + bb * PROG_STRIDE, __ATOMIC_RELAXED, __HIP_MEMORY_SCOPE_AGENT) < 1024)
        __builtin_amdgcn_s_sleep(64);
    }
    __syncthreads();
    __builtin_amdgcn_s_setprio(1);
    const unsigned* p1u = (const unsigned*)P.p1 + (size_t)bb * 3072;
    for (int i = tid; i < 1024; i += 256) {
      float xx = __uint_as_float(__hip_atomic_load(p1u + 3 * i + 0, __ATOMIC_RELAXED, __HIP_MEMORY_SCOPE_AGENT));
      float yy = __uint_as_float(__hip_atomic_load(p1u + 3 * i + 1, __ATOMIC_RELAXED, __HIP_MEMORY_SCOPE_AGENT));
      float zz = __uint_as_float(__hip_atomic_load(p1u + 3 * i + 2, __ATOMIC_RELAXED, __HIP_MEMORY_SCOPE_AGENT));
      q4[i] = float4{xx, yy, zz, 0.f};
    }
    __syncthreads();
    fps2_core(q4, carr, kv2, P.p2 + (size_t)bb * 768, tid, w, lane);
    return;
  }
  // ----------------------- sa1 consumer -----------------------
  const int cid = blockIdx.x - 32;
  for (int blk = cid; blk < P.nprep; blk += P.ncons)
    do_prep_chunk(P.jb, blk, tid);  // sa2/gsa weight prep (no intra-kernel consumer)
  // producer-CU isolation: exit if co-resident with a producer
  int* sh_bail = (int*)(lds + 37152);
  if (tid == 0) {
    unsigned mycu = read_cu_id();
    while (__hip_atomic_load(P.pubcnt, __ATOMIC_ACQUIRE, __HIP_MEMORY_SCOPE_AGENT) < 16)
      __builtin_amdgcn_s_sleep(8);
    int bail = 0;
#pragma unroll
    for (int i = 0; i < 16; ++i) {
      unsigned pc = (unsigned)__hip_atomic_load(P.pcuid + i, __ATOMIC_RELAXED, __HIP_MEMORY_SCOPE_AGENT);
      if (pc == mycu) bail = 1;
    }
    sh_bail[0] = bail;
  }
  __syncthreads();
  if (sh_bail[0]) return;  // block-uniform
  unsigned short* bufA_hi = (unsigned short*)lds;
  unsigned short* bufA_lo = (unsigned short*)(lds + 9216);
  unsigned short* bufB_hi = (unsigned short*)(lds + 18432);
  unsigned short* bufB_lo = (unsigned short*)(lds + 27648);
  int* nb = (int*)(lds + 36864);
  int* tot = (int*)(lds + 37120);
  int* sh_w = (int*)(lds + 37136);
  float* shc = (float*)(lds + 37140);
  const unsigned* p1u = (const unsigned*)P.p1;
  for (;;) {
    if (tid == 0) sh_w[0] = atomicAdd(P.wctr, 1);
    __syncthreads();
    int iw = sh_w[0];
    if (iw >= 16384) break;  // uniform
    int s = iw >> 4, b = iw & 15;  // center-major: matches production order
    if (tid == 0) {
      while (__hip_atomic_load(P.prog + b * PROG_STRIDE, __ATOMIC_RELAXED, __HIP_MEMORY_SCOPE_AGENT) <= s)
        __builtin_amdgcn_s_sleep(16);
      const unsigned* cp = p1u + (size_t)b * 3072 + 3 * s;
      shc[0] = __uint_as_float(__hip_atomic_load(cp + 0, __ATOMIC_RELAXED, __HIP_MEMORY_SCOPE_AGENT));
      shc[1] = __uint_as_float(__hip_atomic_load(cp + 1, __ATOMIC_RELAXED, __HIP_MEMORY_SCOPE_AGENT));
      shc[2] = __uint_as_float(__hip_atomic_load(cp + 2, __ATOMIC_RELAXED, __HIP_MEMORY_SCOPE_AGENT));
    }
    __syncthreads();
    sa1_body(b, b * 1024 + s, shc[0], shc[1], shc[2], P.x, P.pos, P.w1h, P.w1l,
             P.w2h, P.w2l, P.w3h, P.w3l, P.b1, P.b2, P.b3, P.x1, bufA_hi,
             bufA_lo, bufB_hi, bufB_lo, nb, tot);
    __syncthreads();  // protect LDS (sh_w/shc/bufs) reuse across items
  }
}

// ---------------------------------------------------------------------------
// SA2 (MFMA, wave=n-slice): register-mask ball query + MLP + maxpool.
// ---------------------------------------------------------------------------
__global__ __launch_bounds__(256, 2) void sa2_kernel(
    const float* __restrict__ x1,   // [16][1024][128]
    const float* __restrict__ pos1, // [16][1024][3]
    const float* __restrict__ ctr,  // [16][256][3]
    const unsigned short* __restrict__ w1h, const unsigned short* __restrict__ w1l,
    const unsigned short* __restrict__ w2h, const unsigned short* __restrict__ w2l,
    const unsigned short* __restrict__ w3h, const unsigned short* __restrict__ w3l,
    const float* __restrict__ b1, const float* __restrict__ b2,
    const float* __restrict__ b3,
    float* __restrict__ out)        // [16][256][256]
{
  const int N = 1024;
  const float r2 = (float)(0.4 * 0.4);
  const int bs = blockIdx.x;
  const int b = bs >> 8;
  const int tid = threadIdx.x;
  const int w = tid >> 6, lane = tid & 63;
  const float cx = ctr[bs * 3 + 0], cy = ctr[bs * 3 + 1], cz = ctr[bs * 3 + 2];
  __shared__ __align__(16) unsigned short bufA_hi[64 * 168], bufA_lo[64 * 168];
  __shared__ __align__(16) unsigned short bufB_hi[64 * 136], bufB_lo[64 * 136];
  __shared__ int nb[64];
  __shared__ int tot[4];
  nb[lane] = 0;
  unsigned long long mloc[4];
  {
#pragma clang fp contract(off)
#pragma unroll
    for (int it = 0; it < 4; ++it) {
      int i = (w * 4 + it) * 64 + lane;
      const float* p = pos1 + ((size_t)b * N + i) * 3;
      float dx = p[0] - cx, dy = p[1] - cy, dz = p[2] - cz;
      float t0 = dx * dx, t1 = dy * dy, t2 = dz * dz;
      float d2 = (t0 + t1) + t2;
      mloc[it] = __ballot(d2 <= r2);
    }
  }
  {
    int mytot = 0;
#pragma unroll
    for (int it = 0; it < 4; ++it) mytot += (int)__popcll(mloc[it]);
    if (lane == 0) tot[w] = mytot;
  }
  __syncthreads();
  const int t0s = tot[0], t1s = tot[1], t2s = tot[2], t3s = tot[3];
  {
    int cnt = (w > 0 ? t0s : 0) + (w > 1 ? t1s : 0) + (w > 2 ? t2s : 0);
#pragma unroll
    for (int it = 0; it < 4; ++it) {
      unsigned long long m = mloc[it];
      bool inr = (m >> lane) & 1;
      int posn = cnt + (int)__popcll(m & ((1ull << lane) - 1ull));
      if (inr && posn < 64) nb[posn] = (w * 4 + it) * 64 + lane;
      cnt += (int)__popcll(m);
    }
  }
  const int total = t0s + t1s + t2s + t3s;
  const int nvalid = total < 64 ? total : 64;
  __syncthreads();  // nb complete & visible
  {  // stage features: quarter w loads k in [32w, 32w+32); w0 also rel+pad
    int j = nb[lane];
    const float* xr = x1 + ((size_t)b * N + j) * 128 + 32 * w;
#pragma unroll
    for (int g = 0; g < 8; ++g) {
      float4 v = *(const float4*)(xr + 4 * g);
      float vv[4] = {v.x, v.y, v.z, v.w};
#pragma unroll
      for (int e = 0; e < 4; ++e) {
        unsigned short h, l;
        split_bf(vv[e], h, l);
        int k = 32 * w + 4 * g + e;
        bufA_hi[lane * 168 + k] = h;
        bufA_lo[lane * 168 + k] = l;
      }
    }
    if (w == 0) {
      const float* pr = pos1 + ((size_t)b * N + j) * 3;
      float rr[3] = {pr[0] - cx, pr[1] - cy, pr[2] - cz};
#pragma unroll
      for (int c = 0; c < 3; ++c) {
        unsigned short h, l;
        split_bf(rr[c], h, l);
        bufA_hi[lane * 168 + 128 + c] = h;
        bufA_lo[lane * 168 + 128 + c] = l;
      }
#pragma unroll
      for (int k = 131; k < 160; ++k) {
        bufA_hi[lane * 168 + k] = 0;
        bufA_lo[lane * 168 + k] = 0;
      }
    }
  }
  __syncthreads();
  {  // L1: K=160(131), N=128; n-slice [w*32, w*32+32)
    f32x4 acc[4][2];
    mfma_allm<5, 2>(bufA_hi, bufA_lo, 168, w1h, w1l, 168, b1, w * 32, lane, acc);
    store_allm<2>(acc, w * 32, bufB_hi, bufB_lo, 136, lane);
  }
  __syncthreads();
  {  // L2: K=128, N=128; reads B, writes A
    f32x4 acc[4][2];
    mfma_allm<4, 2>(bufB_hi, bufB_lo, 136, w2h, w2l, 136, b2, w * 32, lane, acc);
    store_allm<2>(acc, w * 32, bufA_hi, bufA_lo, 168, lane);
  }
  __syncthreads();
  {  // L3: K=128, N=256; n-slice [w*64, w*64+64) + pool
    f32x4 acc[4][4];
    mfma_allm<4, 4>(bufA_hi, bufA_lo, 168, w3h, w3l, 136, b3, w * 64, lane, acc);
    outpool_allm<4>(acc, w * 64, out + (size_t)bs * 256, nvalid, lane);
  }
}

// ---------------------------------------------------------------------------
// Global SA (MFMA): MLP 259->256->512->1024, 16 points/block, wave=n-quarter.
// ---------------------------------------------------------------------------
__global__ __launch_bounds__(256, 2) void gsa_kernel(
    const float* __restrict__ x2,  // [16][256][256]
    const float* __restrict__ p2,  // [16][256][3]
    const unsigned short* __restrict__ g1h, const unsigned short* __restrict__ g1l,
    const unsigned short* __restrict__ g2h, const unsigned short* __restrict__ g2l,
    const unsigned short* __restrict__ g3h, const unsigned short* __restrict__ g3l,
    const float* __restrict__ b1, const float* __restrict__ b2,
    const float* __restrict__ b3,
    float* __restrict__ part)      // [16][16][1024]
{
  const int blk = blockIdx.x;  // 256
  const int bt = blk >> 4, gidx = blk & 15;
  const int tid = threadIdx.x;
  const int w = tid >> 6, lane = tid & 63;
  const int p0 = gidx * 16;
  __shared__ __align__(16) unsigned short inH[16 * 296], inL[16 * 296];
  __shared__ __align__(16) unsigned short h1H[16 * 264], h1L[16 * 264];
  __shared__ __align__(16) unsigned short h2H[16 * 520], h2L[16 * 520];
  {  // stage 16 points x 256 feats + 3 pos + zero pad to 288
    int p = tid >> 4, seg = tid & 15;
    const float* xr = x2 + ((size_t)(bt * 256 + p0 + p)) * 256 + seg * 16;
#pragma unroll
    for (int g = 0; g < 4; ++g) {
      float4 v = *(const float4*)(xr + 4 * g);
      float vv[4] = {v.x, v.y, v.z, v.w};
#pragma unroll
      for (int e = 0; e < 4; ++e) {
        unsigned short h, l;
        split_bf(vv[e], h, l);
        int k = seg * 16 + 4 * g + e;
        inH[p * 296 + k] = h;
        inL[p * 296 + k] = l;
      }
    }
    if (tid < 16) {
      const float* pr = p2 + (bt * 256 + p0 + tid) * 3;
#pragma unroll
      for (int c = 0; c < 3; ++c) {
        unsigned short h, l;
        split_bf(pr[c], h, l);
        inH[tid * 296 + 256 + c] = h;
        inL[tid * 296 + 256 + c] = l;
      }
      for (int k = 259; k < 288; ++k) {
        inH[tid * 296 + k] = 0;
        inL[tid * 296 + k] = 0;
      }
    }
  }
  __syncthreads();
  {  // L1: K=288(259), N=256
    f32x4 acc[4];
    mfma_1m<9, 4>(inH, inL, 296, g1h, g1l, 296, b1, w * 64, lane, acc);
    store_1m<4>(acc, w * 64, h1H, h1L, 264, lane);
  }
  __syncthreads();
  {  // L2: K=256, N=512
    f32x4 acc[8];
    mfma_1m<8, 8>(h1H, h1L, 264, g2h, g2l, 264, b2, w * 128, lane, acc);
    store_1m<8>(acc, w * 128, h2H, h2L, 520, lane);
  }
  __syncthreads();
  {  // L3: K=512, N=1024 + max over 16 points
    f32x4 acc[16];
    mfma_1m<16, 16>(h2H, h2L, 520, g3h, g3l, 520, b3, w * 256, lane, acc);
    const int col = lane & 15;
    float* op = part + ((size_t)(bt * 16 + gidx)) * 1024 + w * 256;
#pragma unroll
    for (int t = 0; t < 16; ++t) {
      float m = -DEVINF;
#pragma unroll
      for (int r = 0; r < 4; ++r) m = fmaxf(m, fmaxf(acc[t][r], 0.f));
      m = fmaxf(m, __shfl_xor(m, 16, 64));
      m = fmaxf(m, __shfl_xor(m, 32, 64));
      if ((lane >> 4) == 0) op[t * 16 + col] = m;
    }
  }
}

// ---------------------------------------------------------------------------
// head1: gmax + l1 + l2 + l3. One block per B-row (16 blocks).
// ---------------------------------------------------------------------------
__global__ __launch_bounds__(256) void head1_kernel(
    const float* __restrict__ part,  // [16][16][1024]
    const float* __restrict__ l1w, const float* __restrict__ l1b,
    const float* __restrict__ l2w, const float* __restrict__ l2b,
    const float* __restrict__ l3w, const float* __restrict__ l3b,
    float* __restrict__ hC)          // [16][256]
{
  const int m = blockIdx.x;
  const int tid = threadIdx.x;
  __shared__ float gA[1024];
  __shared__ float hX[512];
  __shared__ float hY[256];
#pragma unroll
  for (int j = 0; j < 4; ++j) {
    int c = j * 256 + tid;
    float mx = -DEVINF;
#pragma unroll
    for (int t = 0; t < 16; ++t)
      mx = fmaxf(mx, part[((size_t)(m * 16 + t)) * 1024 + c]);
    gA[c] = mx;
  }
  __syncthreads();
  {  // l1: 1024 -> 512, relu
    float a0 = l1b[tid], a1 = l1b[tid + 256];
#pragma unroll 4
    for (int k = 0; k < 1024; ++k) {
      float v = gA[k];
      a0 = fmaf(v, l1w[(size_t)k * 512 + tid], a0);
      a1 = fmaf(v, l1w[(size_t)k * 512 + tid + 256], a1);
    }
    hX[tid] = fmaxf(a0, 0.f);
    hX[tid + 256] = fmaxf(a1, 0.f);
  }
  __syncthreads();
  {  // l2: 512 -> 256, relu
    float a = l2b[tid];
#pragma unroll 4
    for (int k = 0; k < 512; ++k) a = fmaf(hX[k], l2w[(size_t)k * 256 + tid], a);
    hY[tid] = fmaxf(a, 0.f);
  }
  __syncthreads();
  {  // l3: 256 -> 256, no relu
    float a = l3b[tid];
#pragma unroll 4
    for (int k = 0; k < 256; ++k) a = fmaf(hY[k], l3w[(size_t)k * 256 + tid], a);
    hC[(size_t)m * 256 + tid] = a;
  }
}

// ---------------------------------------------------------------------------
// head2: fusion MLP (fw1,fw2,fw3) + l4 + l5. One block per fused row (4).
// ---------------------------------------------------------------------------
__global__ __launch_bounds__(256) void head2_kernel(
    const float* __restrict__ hC,  // [4][1024]
    const float* __restrict__ fw1, const float* __restrict__ fb1,
    const float* __restrict__ fw2, const float* __restrict__ fb2,
    const float* __restrict__ fw3, const float* __restrict__ fb3,
    const float* __restrict__ l4w, const float* __restrict__ l4b,
    const float* __restrict__ l5w, const float* __restrict__ l5b,
    float* __restrict__ out)       // [4][128]
{
  const int m = blockIdx.x;
  const int tid = threadIdx.x;
  __shared__ float A[1024];
  __shared__ float Bf[512];
#pragma unroll
  for (int j = 0; j < 4; ++j) A[j * 256 + tid] = hC[(size_t)m * 1024 + j * 256 + tid];
  __syncthreads();
  {  // fw1: 1024 -> 512 relu, A -> Bf
    float a0 = fb1[tid], a1 = fb1[tid + 256];
#pragma unroll 4
    for (int k = 0; k < 1024; ++k) {
      float v = A[k];
      a0 = fmaf(v, fw1[(size_t)k * 512 + tid], a0);
      a1 = fmaf(v, fw1[(size_t)k * 512 + tid + 256], a1);
    }
    Bf[tid] = fmaxf(a0, 0.f);
    Bf[tid + 256] = fmaxf(a1, 0.f);
  }
  __syncthreads();
  {  // fw2: 512 -> 512 relu, Bf -> A
    float a0 = fb2[tid], a1 = fb2[tid + 256];
#pragma unroll 4
    for (int k = 0; k < 512; ++k) {
      float v = Bf[k];
      a0 = fmaf(v, fw2[(size_t)k * 512 + tid], a0);
      a1 = fmaf(v, fw2[(size_t)k * 512 + tid + 256], a1);
    }
    __syncthreads();
    A[tid] = fmaxf(a0, 0.f);
    A[tid + 256] = fmaxf(a1, 0.f);
  }
  __syncthreads();
  {  // fw3: 512 -> 256 relu, A -> Bf
    float a = fb3[tid];
#pragma unroll 4
    for (int k = 0; k < 512; ++k) a = fmaf(A[k], fw3[(size_t)k * 256 + tid], a);
    __syncthreads();
    Bf[tid] = fmaxf(a, 0.f);
  }
  __syncthreads();
  {  // l4: 256 -> 128 relu, Bf -> A
    if (tid < 128) {
      float a = l4b[tid];
#pragma unroll 4
      for (int k = 0; k < 256; ++k) a = fmaf(Bf[k], l4w[(size_t)k * 128 + tid], a);
      A[tid] = fmaxf(a, 0.f);
    }
  }
  __syncthreads();
  {  // l5: 128 -> 128, A -> out
    if (tid < 128) {
      float a = l5b[tid];
#pragma unroll 4
      for (int k = 0; k < 128; ++k) a = fmaf(A[k], l5w[(size_t)k * 128 + tid], a);
      out[(size_t)m * 128 + tid] = a;
    }
  }
}

// ---------------------------------------------------------------------------
extern "C" void kernel_launch(void* const* d_in, const int* in_sizes, int n_in,
                              void* d_out, int out_size, void* d_ws, size_t ws_size,
                              hipStream_t stream) {
  (void)in_sizes; (void)n_in; (void)out_size;
  const float* x    = (const float*)d_in[0];
  const float* pos  = (const float*)d_in[1];
  const float* s1w1 = (const float*)d_in[2];  const float* s1b1 = (const float*)d_in[3];
  const float* s1w2 = (const float*)d_in[4];  const float* s1b2 = (const float*)d_in[5];
  const float* s1w3 = (const float*)d_in[6];  const float* s1b3 = (const float*)d_in[7];
  const float* s2w1 = (const float*)d_in[8];  const float* s2b1 = (const float*)d_in[9];
  const float* s2w2 = (const float*)d_in[10]; const float* s2b2 = (const float*)d_in[11];
  const float* s2w3 = (const float*)d_in[12]; const float* s2b3 = (const float*)d_in[13];
  const float* s3w1 = (const float*)d_in[14]; const float* s3b1 = (const float*)d_in[15];
  const float* s3w2 = (const float*)d_in[16]; const float* s3b2 = (const float*)d_in[17];
  const float* s3w3 = (const float*)d_in[18]; const float* s3b3 = (const float*)d_in[19];
  const float* fw1  = (const float*)d_in[20]; const float* fb1  = (const float*)d_in[21];
  const float* fw2  = (const float*)d_in[22]; const float* fb2  = (const float*)d_in[23];
  const float* fw3  = (const float*)d_in[24]; const float* fb3  = (const float*)d_in[25];
  const float* l1w  = (const float*)d_in[26]; const float* l1b  = (const float*)d_in[27];
  const float* l2w  = (const float*)d_in[28]; const float* l2b  = (const float*)d_in[29];
  const float* l3w  = (const float*)d_in[30]; const float* l3b  = (const float*)d_in[31];
  const float* l4w  = (const float*)d_in[32]; const float* l4b  = (const float*)d_in[33];
  const float* l5w  = (const float*)d_in[34]; const float* l5b  = (const float*)d_in[35];
  float* out = (float*)d_out;

  float* ws = (float*)d_ws;
  float* p1   = ws;                  // 16*1024*3
  float* x1   = p1 + 49152;          // 16*1024*128
  float* p2   = x1 + 2097152;        // 16*256*3
  float* x2   = p2 + 12288;          // 16*256*256
  float* part = x2 + 1048576;        // 16*16*1024
  float* hC   = part + 262144;       // 16*256
  // bf16 hi/lo transposed weight planes (u16)
  unsigned short* wp = (unsigned short*)(hC + 4096);
  unsigned short* s1w1h = wp;              unsigned short* s1w1l = s1w1h + 2560;    // [64][40]
  unsigned short* s1w2h = s1w1l + 2560;    unsigned short* s1w2l = s1w2h + 4608;    // [64][72]
  unsigned short* s1w3h = s1w2l + 4608;    unsigned short* s1w3l = s1w3h + 9216;    // [128][72]
  unsigned short* s2w1h = s1w3l + 9216;    unsigned short* s2w1l = s2w1h + 21504;   // [128][168]
  unsigned short* s2w2h = s2w1l + 21504;   unsigned short* s2w2l = s2w2h + 17408;   // [128][136]
  unsigned short* s2w3h = s2w2l + 17408;   unsigned short* s2w3l = s2w3h + 34816;   // [256][136]
  unsigned short* g1h   = s2w3l + 34816;   unsigned short* g1l   = g1h + 75776;     // [256][296]
  unsigned short* g2h   = g1l + 75776;     unsigned short* g2l   = g2h + 135168;    // [512][264]
  unsigned short* g3h   = g2l + 135168;    unsigned short* g3l   = g3h + 532480;    // [1024][520]
  // control block: padded prog[16*32] + wctr + pcuid[16] + pubcnt
  int* ctrl = (int*)(g3l + 532480);
  int* prog = ctrl;                        // [16 * PROG_STRIDE]
  int* wctr = ctrl + 16 * PROG_STRIDE;     // [1]
  int* pcuid = wctr + 4;                   // [16] (4-int gap keeps wctr on own 16B)
  int* pubcnt = pcuid + 16;                // [1]

  // jbA: s1 weights (needed by fused consumers -> pre-kernel)
  PrepJobs jbA{};
  {
    const float* s[3] = {s1w1, s1w2, s1w3};
    unsigned short* hs[3] = {s1w1h, s1w2h, s1w3h};
    unsigned short* ls[3] = {s1w1l, s1w2l, s1w3l};
    int Ks[3] = {12, 64, 64}, Ns[3] = {64, 64, 128}, rls[3] = {40, 72, 72};
    int acc = 0;
    for (int j = 0; j < 3; ++j) {
      jbA.src[j] = s[j]; jbA.hi[j] = hs[j]; jbA.lo[j] = ls[j];
      jbA.K[j] = Ks[j]; jbA.N[j] = Ns[j]; jbA.rl[j] = rls[j];
      jbA.blk0[j] = acc;
      acc += (Ns[j] * rls[j] + 255) / 256;
    }
    for (int j = 3; j < 9; ++j) jbA.blk0[j] = 0x7fffffff;
    jbA.blk0[9] = acc;  // 64
  }
  // jbB: sa2/gsa weights (done by fused consumers, or fallback prep kernel)
  PrepJobs jbB{};
  int accB = 0;
  {
    const float* s[6] = {s2w1, s2w2, s2w3, s3w1, s3w2, s3w3};
    unsigned short* hs[6] = {s2w1h, s2w2h, s2w3h, g1h, g2h, g3h};
    unsigned short* ls[6] = {s2w1l, s2w2l, s2w3l, g1l, g2l, g3l};
    int Ks[6] = {131, 128, 128, 259, 256, 512};
    int Ns[6] = {128, 128, 256, 256, 512, 1024};
    int rls[6] = {168, 136, 136, 296, 264, 520};
    for (int j = 0; j < 6; ++j) {
      jbB.src[j] = s[j]; jbB.hi[j] = hs[j]; jbB.lo[j] = ls[j];
      jbB.K[j] = Ks[j]; jbB.N[j] = Ns[j]; jbB.rl[j] = rls[j];
      jbB.blk0[j] = accB;
      accB += (Ns[j] * rls[j] + 255) / 256;
    }
    for (int j = 6; j < 9; ++j) jbB.blk0[j] = 0x7fffffff;
    jbB.blk0[9] = accB;  // 3192
  }

  // --- fused cooperative path (fps1 || sa1, fps2 tail), with safe fallback ---
  // ctrl block = (16*32 + 4 + 16 + 1 + pad) ints; layout end:
  bool try_coop = (ws_size >= 17230016ull);
  static int gblocks = -2;
  if (try_coop) {
    if (gblocks == -2) {
      int dev = 0;
      (void)hipGetDevice(&dev);
      int ncu = 0;
      (void)hipDeviceGetAttribute(&ncu, hipDeviceAttributeMultiprocessorCount, dev);
      int maxb = 0;
      (void)hipOccupancyMaxActiveBlocksPerMultiprocessor(&maxb, (const void*)fused_kernel, 256, 0);
      gblocks = (ncu > 0 && maxb > 0) ? ncu * maxb : -1;
    }
    if (gblocks < 64) try_coop = false;
  }
  bool coop_done = false;
  bool prepA_done = false;
  if (try_coop) {
    hipMemsetAsync(ctrl, 0, (16 * PROG_STRIDE + 24) * sizeof(int), stream);
    prep_kernel<<<64, 256, 0, stream>>>(jbA);
    prepA_done = true;
    FusedParams fp;
    fp.x = x; fp.pos = pos; fp.p1 = p1; fp.p2 = p2;
    fp.w1h = s1w1h; fp.w1l = s1w1l; fp.w2h = s1w2h; fp.w2l = s1w2l;
    fp.w3h = s1w3h; fp.w3l = s1w3l;
    fp.b1 = s1b1; fp.b2 = s1b2; fp.b3 = s1b3;
    fp.x1 = x1; fp.prog = prog; fp.wctr = wctr;
    fp.pcuid = pcuid; fp.pubcnt = pubcnt;
    fp.jb = jbB; fp.nprep = accB; fp.ncons = gblocks - 32;
    void* kargs[] = {(void*)&fp};
    hipError_t e = hipLaunchCooperativeKernel((const void*)fused_kernel,
                                              dim3((unsigned)gblocks), dim3(256),
                                              kargs, 0, stream);
    coop_done = (e == hipSuccess);
  }
  if (!coop_done) {
    if (!prepA_done) prep_kernel<<<64, 256, 0, stream>>>(jbA);
    prep_kernel<<<accB, 256, 0, stream>>>(jbB);
    fps1_kernel<<<16, 256, 0, stream>>>(pos, p1);
    sa1_kernel<<<16 * 1024 + 16, 256, 0, stream>>>(x, pos, p1, p2, s1w1h, s1w1l,
                                                   s1w2h, s1w2l, s1w3h, s1w3l,
                                                   s1b1, s1b2, s1b3, x1);
  }
  sa2_kernel<<<16 * 256, 256, 0, stream>>>(x1, p1, p2, s2w1h, s2w1l, s2w2h,
                                           s2w2l, s2w3h, s2w3l, s2b1, s2b2,
                                           s2b3, x2);
  gsa_kernel<<<256, 256, 0, stream>>>(x2, p2, g1h, g1l, g2h, g2l, g3h, g3l,
                                      s3b1, s3b2, s3b3, part);
  head1_kernel<<<16, 256, 0, stream>>>(part, l1w, l1b, l2w, l2b, l3w, l3b, hC);
  head2_kernel<<<4, 256, 0, stream>>>(hC, fw1, fb1, fw2, fb2, fw3, fb3, l4w,
                                      l4b, l5w, l5b, out);
}